// Round 14
// baseline (4074.996 us; speedup 1.0000x reference)
//
#include <hip/hip_runtime.h>
#include <math.h>

#define HF 32
#define WF 128
#define HW 4096
#define C_DIM 684
#define H_DIM 256
#define A_DIM 512
#define V_DIM 415
#define PADR 42
#define PADC 144
#define T_STEPS 64

#define NERG 128
#define CTX0 128
#define NCTXB 86
#define MONO 214
#define RED0 215   // 8 reducers 215..222
#define TAIL0 223  // 16 tail 223..238
#define HEAT0 239  // 16 heaters 239..254
#define NGRID 255

// ---------------- workspace layout (float offsets) ----------------
constexpr int CT_OFF      = 0;                        // [4096][512]
constexpr int KMT_OFF     = CT_OFF + HW * A_DIM;      // [512][121]
constexpr int APAD_OFF    = KMT_OFF + 61952;          // [42][144] mutable
constexpr int MASK_OFF    = APAD_OFF + 6048;
constexpr int PART_OFF    = MASK_OFF + 4096;          // [4][4096] mutable
constexpr int AVG_OFF     = PART_OFF + 16384;         // 704
constexpr int H0_OFF      = AVG_OFF + 704;            // 256
constexpr int QV_OFF      = H0_OFF + 256;             // [512] mutable
constexpr int H1V_OFF     = QV_OFF + 512;             // [2][256] mutable
constexpr int GHOV_OFF    = H1V_OFF + 512;            // [2][768] mutable
constexpr int GHNV_OFF    = GHOV_OFF + 1536;          // [768] mutable
constexpr int GS_OFF      = GHNV_OFF + 768;           // [8][768] mutable
constexpr int GPS_OFF     = GS_OFF + 6144;            // [8][128] mutable
constexpr int CTXV_OFF    = GPS_OFF + 1024;           // [86][8] mutable (pad 704)
constexpr int MSUM_OFF    = CTXV_OFF + 704;           // 16
// ---- contiguous SYNC region (cleared by k_init in one loop) ----
constexpr int FLAGS_OFF   = MSUM_OFF + 16;            // 256 lines x16: EF 0..127, CF 128..213, TF 224..239
constexpr int AFR_OFF     = FLAGS_OFF + 4096;         // 8 x16
constexpr int AF2R_OFF    = AFR_OFF + 128;            // 8 x16
constexpr int H1F_OFF     = AF2R_OFF + 128;           // 8 x16
constexpr int DONE_OFF    = H1F_OFF + 128;            // 8 x16
constexpr int GFR_OFF     = DONE_OFF + 128;           // [8 j][8 r] x16 = 1024
constexpr int TQR_OFF     = GFR_OFF + 1024;           // [16 s][8 r] x16 = 2048
constexpr int SYNC_END    = TQR_OFF + 2048;           // 7680 ints from FLAGS_OFF
// ---- read-only tables ----
constexpr int GI_OFF      = SYNC_END;                 // [415][768]
constexpr int SE_OFF      = GI_OFF + V_DIM * 768;     // [415][128]
constexpr int WIHTOUT_OFF = SE_OFF + V_DIM * 128;     // [684][768]
constexpr int WCT_OFF     = WIHTOUT_OFF + 684 * 768;  // [684][128]
constexpr int WST_OFF     = WCT_OFF + 684 * 128;      // [256][128]
constexpr int WVT_OFF     = WST_OFF + 256 * 128;      // [128][415]
constexpr int WS_END      = WVT_OFF + 128 * V_DIM;

__device__ __forceinline__ float sigmoidf_(float x) { return 1.f / (1.f + expf(-x)); }
__device__ __forceinline__ float ftanh(float x) {
  float e = __expf(2.f * x);
  return 1.f - 2.f / (e + 1.f);
}

__device__ __forceinline__ float gld(const float* p) {
  int v = __hip_atomic_load((const int*)p, __ATOMIC_RELAXED, __HIP_MEMORY_SCOPE_AGENT);
  return __int_as_float(v);
}
__device__ __forceinline__ void gst(float* p, float x) {
  __hip_atomic_store((int*)p, __float_as_int(x), __ATOMIC_RELAXED, __HIP_MEMORY_SCOPE_AGENT);
}
__device__ __forceinline__ void pollf(int* p, int ph) {
  int it = 0;
  while (__hip_atomic_load(p, __ATOMIC_RELAXED, __HIP_MEMORY_SCOPE_AGENT) < ph) {
    if (it < 4) __builtin_amdgcn_s_sleep(1);
    else if (it < 16) __builtin_amdgcn_s_sleep(4);
    else __builtin_amdgcn_s_sleep(8);
    ++it;
  }
  asm volatile("" ::: "memory");
}
__device__ __forceinline__ void rel_store(int* p, int v) {
  __hip_atomic_store(p, v, __ATOMIC_RELEASE, __HIP_MEMORY_SCOPE_AGENT);
}

// ---------------- precompute ----------------

__global__ void k_init(const float* __restrict__ imask, float* ws) {
  __shared__ float red[4];
  int tid = threadIdx.x;
  float s = 0.f;
  for (int i = tid; i < HW; i += 256) {
    int h = i >> 7, w = i & 127;
    float m = imask[h * 16 * 2048 + w * 16];
    ws[MASK_OFF + i] = m;
    s += m;
  }
  for (int i = tid; i < PADR * PADC; i += 256) ws[APAD_OFF + i] = 0.f;
  int* sync = (int*)(ws + FLAGS_OFF);
  for (int i = tid; i < 7680; i += 256) sync[i] = 0;  // FULL sync-region reset
#pragma unroll
  for (int off = 32; off; off >>= 1) s += __shfl_xor(s, off, 64);
  if ((tid & 63) == 0) red[tid >> 6] = s;
  __syncthreads();
  if (tid == 0) ws[MSUM_OFF] = red[0] + red[1] + red[2] + red[3];
}

__global__ void k_avg(const float* __restrict__ cnn, float* ws) {
  __shared__ float red[4];
  int c = blockIdx.x, tid = threadIdx.x;
  const float* row = cnn + c * HW;
  float s = 0.f;
  for (int i = tid; i < HW; i += 256) s += ws[MASK_OFF + i] * row[i];
#pragma unroll
  for (int off = 32; off; off >>= 1) s += __shfl_xor(s, off, 64);
  if ((tid & 63) == 0) red[tid >> 6] = s;
  __syncthreads();
  if (tid == 0) ws[AVG_OFF + c] = (red[0] + red[1] + red[2] + red[3]) / ws[MSUM_OFF];
}

__global__ void k_h0(const float* __restrict__ W_init, const float* __restrict__ b_init, float* ws) {
  __shared__ float a_s[C_DIM];
  int tid = threadIdx.x;
  for (int i = tid; i < C_DIM; i += 256) a_s[i] = ws[AVG_OFF + i];
  __syncthreads();
  const float* wr = W_init + tid * C_DIM;
  float s = b_init[tid];
  for (int k = 0; k < C_DIM; k++) s += a_s[k] * wr[k];
  ws[H0_OFF + tid] = tanhf(s);
}

__global__ __launch_bounds__(512) void k_km(const float* __restrict__ convk,
                                            const float* __restrict__ Wcov, float* ws) {
  __shared__ float kt[256];
  int t = blockIdx.x, a = threadIdx.x;
  if (a < 256) kt[a] = convk[a * 121 + t];
  __syncthreads();
  const float* wr = Wcov + a * 256;
  float s = 0.f;
  for (int c = 0; c < 256; c++) s += kt[c] * wr[c];
  ws[KMT_OFF + a * 121 + t] = s;
}

__global__ void k_ct(const float* __restrict__ cnn, const float* __restrict__ Wproj,
                     const float* __restrict__ bproj, float* ws) {
  __shared__ float As[8][128];
  __shared__ float Bs[8][64];
  int hw0 = blockIdx.x * 128;
  int a0 = blockIdx.y * 64;
  int tid = threadIdx.x;
  int tx = tid & 15, ty = tid >> 4;
  float acc[8][4];
#pragma unroll
  for (int i = 0; i < 8; i++)
#pragma unroll
    for (int j = 0; j < 4; j++) acc[i][j] = 0.f;
  for (int c0 = 0; c0 < C_DIM; c0 += 8) {
    {
      int kk = tid >> 5;
      int m4 = (tid & 31) * 4;
      int c = c0 + kk;
      float4 v = make_float4(0.f, 0.f, 0.f, 0.f);
      if (c < C_DIM) v = *(const float4*)(cnn + c * HW + hw0 + m4);
      *(float4*)&As[kk][m4] = v;
    }
    {
      int n = tid & 63;
      int kk0 = (tid >> 6) * 2;
      const float* wr = Wproj + (a0 + n) * C_DIM + c0;
      Bs[kk0][n]     = (c0 + kk0 < C_DIM) ? wr[kk0] : 0.f;
      Bs[kk0 + 1][n] = (c0 + kk0 + 1 < C_DIM) ? wr[kk0 + 1] : 0.f;
    }
    __syncthreads();
#pragma unroll
    for (int kk = 0; kk < 8; kk++) {
      float a8[8], b4[4];
#pragma unroll
      for (int i = 0; i < 8; i++) a8[i] = As[kk][ty * 8 + i];
#pragma unroll
      for (int j = 0; j < 4; j++) b4[j] = Bs[kk][tx * 4 + j];
#pragma unroll
      for (int i = 0; i < 8; i++)
#pragma unroll
        for (int j = 0; j < 4; j++) acc[i][j] += a8[i] * b4[j];
    }
    __syncthreads();
  }
#pragma unroll
  for (int i = 0; i < 8; i++) {
    int hw = hw0 + ty * 8 + i;
#pragma unroll
    for (int j = 0; j < 4; j++) {
      int a = a0 + tx * 4 + j;
      ws[CT_OFF + hw * A_DIM + a] = acc[i][j] + bproj[a];
    }
  }
}

__global__ void k_gi(const float* __restrict__ emb_table, const float* __restrict__ Wih_in,
                     const float* __restrict__ bih_in, float* ws) {
  __shared__ float e_s[256];
  int v = blockIdx.x, tid = threadIdx.x;
  e_s[tid] = emb_table[v * 256 + tid];
  __syncthreads();
#pragma unroll
  for (int r = 0; r < 3; r++) {
    int m = r * 256 + tid;
    const float* wr = Wih_in + m * 256;
    float s = bih_in[m];
    for (int k = 0; k < 256; k++) s += e_s[k] * wr[k];
    ws[GI_OFF + v * 768 + m] = s;
  }
}

__global__ void k_se(const float* __restrict__ emb_table, const float* __restrict__ We,
                     const float* __restrict__ be, float* ws) {
  __shared__ float e_s[256];
  int v = blockIdx.x, tid = threadIdx.x;  // 128
  e_s[tid] = emb_table[v * 256 + tid];
  e_s[tid + 128] = emb_table[v * 256 + tid + 128];
  __syncthreads();
  const float* wr = We + tid * 256;
  float s = be[tid];
  for (int k = 0; k < 256; k++) s += e_s[k] * wr[k];
  ws[SE_OFF + v * 128 + tid] = s;
}

__global__ void k_tr(const float* __restrict__ in, float* __restrict__ out, int M, int Kd) {
  int total = M * Kd;
  for (int i = blockIdx.x * blockDim.x + threadIdx.x; i < total; i += gridDim.x * blockDim.x) {
    int m = i / Kd, k = i - m * Kd;
    out[k * M + m] = in[i];
  }
}

// bootstrap 1: h1(0) slices -> H1V slot0 (word = 1)
__global__ __launch_bounds__(512) void k_pre0(const float* __restrict__ Whh_in,
                                              const float* __restrict__ bhh_in, float* ws) {
  __shared__ float h0s[256];
  __shared__ float ghn48[48];
  const int s = blockIdx.x, tid = threadIdx.x;
  const int j0 = s * 16;
  if (tid < 256) h0s[tid] = ws[H0_OFF + tid];
  __syncthreads();
  {
    int r = tid >> 3, l = tid & 7;
    if (r < 48) {
      int mg = (r >> 4) * 256 + j0 + (r & 15);
      const float* wr = Whh_in + mg * 256 + l * 32;
      float sm = 0.f;
#pragma unroll
      for (int k = 0; k < 32; k++) sm += h0s[l * 32 + k] * wr[k];
#pragma unroll
      for (int off = 4; off; off >>= 1) sm += __shfl_xor(sm, off, 8);
      if (l == 0) ghn48[r] = sm + bhh_in[mg];
    }
  }
  __syncthreads();
  if (tid < 16) {
    int j = j0 + tid;
    const float* gi = ws + GI_OFF + 1 * 768;
    float r = sigmoidf_(gi[j] + ghn48[tid]);
    float z = sigmoidf_(gi[256 + j] + ghn48[16 + tid]);
    float n = tanhf(gi[512 + j] + r * ghn48[32 + tid]);
    gst(ws + H1V_OFF + j, (1.f - z) * n + z * h0s[j]);  // slot 0
  }
}

// bootstrap 2: q(0) and gho(0) slices from H1V slot0
__global__ __launch_bounds__(512) void k_pre1(const float* __restrict__ Wq,
                                              const float* __restrict__ Whh_out,
                                              const float* __restrict__ bhh_out, float* ws) {
  __shared__ float h1s[256];
  const int s = blockIdx.x, tid = threadIdx.x;
  if (tid < 256) h1s[tid] = gld(ws + H1V_OFF + tid);
  __syncthreads();
  {
    int ap = tid >> 4, l = tid & 15;
    int a = s * 32 + ap;
    const float* wr = Wq + a * 256 + l * 16;
    float sm = 0.f;
#pragma unroll
    for (int k = 0; k < 16; k++) sm += h1s[l * 16 + k] * wr[k];
#pragma unroll
    for (int off = 8; off; off >>= 1) sm += __shfl_xor(sm, off, 16);
    if (l == 0) gst(ws + QV_OFF + a, sm);
  }
  {
    int r = tid >> 3, l = tid & 7;
    if (r < 48) {
      int m = s * 48 + r;
      const float* wr = Whh_out + m * 256 + l * 32;
      float sm = 0.f;
#pragma unroll
      for (int k = 0; k < 32; k++) sm += h1s[l * 32 + k] * wr[k];
#pragma unroll
      for (int off = 4; off; off >>= 1) sm += __shfl_xor(sm, off, 8);
      if (l == 0) gst(ws + GHOV_OFF + m, sm + bhh_out[m]);  // slot 0
    }
  }
}

__global__ void k_go(float* ws) {
  int tid = threadIdx.x;
  if (tid < 128) ((int*)(ws + TQR_OFF))[tid * 16] = 1;  // q(0) ready
}

// ---------------- persistent kernel ----------------
// roles: 0..127 energy; 128..213 ctx; 214 mono; 215..222 reducers; 223..238 tail; 239..254 heaters.
// step t (flag value t+1): TQR>=t+1 -> E tanh -> EF -> mono AFR -> ctx (ctxv only) -> CF ->
//   reducers (gio/psc dots from CTXV -> GS/GPS, af2r, GFR) -> {mono: h,state,prob,word | tail: h, ghn->TF}
//   -> mono h1 -> H1F -> tail: gho(t+1), q(t+1) -> TQR=t+2.

__global__ __launch_bounds__(512) void k_steps(
    const float* __restrict__ cnn, const float* __restrict__ Whh_in,
    const float* __restrict__ Whh_out, const float* __restrict__ Wq,
    const float* __restrict__ bq, const float* __restrict__ wa, const float* __restrict__ ba,
    const float* __restrict__ bih_out, const float* __restrict__ bhh_out,
    const float* __restrict__ bhh_in,
    const float* __restrict__ bs_, const float* __restrict__ bc_, const float* __restrict__ bv_,
    float* ws, float* __restrict__ out) {
  __shared__ __align__(16) float S[40016];

  const int bid = blockIdx.x, tid = threadIdx.x;
  int* flags = (int*)(ws + FLAGS_OFF);
  int* afr   = (int*)(ws + AFR_OFF);
  int* af2r  = (int*)(ws + AF2R_OFF);
  int* h1f   = (int*)(ws + H1F_OFF);
  int* donef = (int*)(ws + DONE_OFF);
  int* gfr   = (int*)(ws + GFR_OFF);
  int* tqr   = (int*)(ws + TQR_OFF);

  if (bid < NERG) {
    // ================= ENERGY =================
    const int h_row = bid >> 2, aq = bid & 3, a0 = aq * 128;
    const int al = tid & 127, hslot = tid >> 7;
    float* km    = S;          // [128][132]
    float* ct    = S + 16896;  // [128][128]
    float* patch = S + 33280;  // [11][144]
    float* maskv = S + 34864;
    float* redE  = S + 34992;
    for (int i = tid; i < 128 * 132; i += 512) {
      int a = i / 132, j = i - a * 132;
      int dy = j / 12, dx = j - dy * 12;
      km[i] = (dx < 11) ? ws[KMT_OFF + (a0 + a) * 121 + dy * 11 + dx] : 0.f;
    }
    for (int i = tid; i < 128 * 128; i += 512) {
      int w = i >> 7, aa = i & 127;
      ct[i] = ws[CT_OFF + (h_row * 128 + w) * 512 + a0 + aa];
    }
    if (tid < 128) maskv[tid] = ws[MASK_OFF + h_row * 128 + tid];
    const float bq_a = bq[a0 + al], wa_a = wa[a0 + al], ba0 = ba[0];
    __syncthreads();

#pragma unroll 1
    for (int t = 0; t < T_STEPS; t++) {
      if (tid == 0) pollf(&af2r[(bid & 7) * 16], t);
      __syncthreads();
      for (int i = tid; i < 11 * 138; i += 512) {
        int r = i / 138, c = i - r * 138;
        patch[r * 144 + c] = gld(ws + APAD_OFF + (h_row + r) * PADC + c);
      }
      __syncthreads();
      float acc[2][16];
#pragma unroll
      for (int p = 0; p < 2; p++)
#pragma unroll
        for (int i = 0; i < 16; i++) acc[p][i] = 0.f;
      const int wbase0 = hslot * 32;
#pragma unroll 1
      for (int dy = 0; dy < 11; dy++) {
        float kv[12];
        {
          const float* kb = &km[al * 132 + dy * 12];
          *(float4*)&kv[0] = *(const float4*)&kb[0];
          *(float4*)&kv[4] = *(const float4*)&kb[4];
          *(float4*)&kv[8] = *(const float4*)&kb[8];
        }
#pragma unroll
        for (int p = 0; p < 2; p++) {
          float row[28];
          const float* pr = &patch[dy * 144 + wbase0 + p * 16];
#pragma unroll
          for (int i = 0; i < 7; i++) *(float4*)&row[i * 4] = *(const float4*)&pr[i * 4];
#pragma unroll
          for (int dx = 0; dx < 11; dx++)
#pragma unroll
            for (int wi = 0; wi < 16; wi++) acc[p][wi] += kv[dx] * row[wi + dx];
        }
      }
      // q gate
      if (tid < 16) pollf(&tqr[(tid * 8 + (bid & 7)) * 16], t + 1);
      __syncthreads();
      float qa = bq_a + gld(ws + QV_OFF + a0 + al);
#pragma unroll 1
      for (int p = 0; p < 2; p++) {
        const int wbase = wbase0 + p * 16;
#pragma unroll
        for (int wi = 0; wi < 16; wi++) {
          float x = acc[p][wi] + qa + ct[(wbase + wi) * 128 + al];
          float v = ftanh(x) * wa_a;
#pragma unroll
          for (int off = 32; off; off >>= 1) v += __shfl_xor(v, off, 64);
          if ((tid & 63) == 0) redE[(tid >> 6) * 16 + wi] = v;
        }
        __syncthreads();
        if (tid < 64) {
          int hs2 = tid >> 4, wi = tid & 15;
          int w = hs2 * 32 + p * 16 + wi;
          float e = redE[(hs2 * 2) * 16 + wi] + redE[(hs2 * 2 + 1) * 16 + wi];
          float val = (maskv[w] > 0.f) ? (e + (aq == 0 ? ba0 : 0.f)) : -2.5e8f;
          gst(ws + PART_OFF + aq * 4096 + h_row * 128 + w, val);
        }
        __syncthreads();
      }
      if (tid == 0) rel_store(&flags[bid * 16], t + 1);
    }

  } else if (bid < CTX0 + NCTXB) {
    // ================= CTX (emits ctxv[8] only) =================
    const int cb = bid - CTX0, c0 = cb * 8;
    float* cnnS = S;           // 32768
    float* redC = S + 32768;   // 64
    float* ctxv = S + 32832;   // 8
    float* invp = S + 32840;
    for (int i = tid; i < 8 * 4096; i += 512) {
      int c = c0 + (i >> 12);
      cnnS[i] = (c < C_DIM) ? cnn[c * 4096 + (i & 4095)] : 0.f;
    }
    __syncthreads();

#pragma unroll 1
    for (int t = 0; t < T_STEPS; t++) {
      if (tid == 0) pollf(&afr[(bid & 7) * 16], t + 1);
      __syncthreads();
      float ev[8];
      float ssum = 0.f;
#pragma unroll
      for (int j = 0; j < 8; j++) {
        int hw = j * 512 + tid;
        float e = gld(ws + PART_OFF + hw) + gld(ws + PART_OFF + 4096 + hw) +
                  gld(ws + PART_OFF + 8192 + hw) + gld(ws + PART_OFF + 12288 + hw);
        ev[j] = __expf(e);
        ssum += ev[j];
      }
#pragma unroll
      for (int off = 32; off; off >>= 1) ssum += __shfl_xor(ssum, off, 64);
      if ((tid & 63) == 0) redC[tid >> 6] = ssum;
      __syncthreads();
      if (tid == 0) {
        float s2 = 0.f;
#pragma unroll
        for (int i = 0; i < 8; i++) s2 += redC[i];
        invp[0] = 1.f / s2;
      }
      __syncthreads();
      float inv = invp[0];
      if (cb < 8) {
        int hw = cb * 512 + tid;
        int hh = hw >> 7, ww = hw & 127;
        float* ap = ws + APAD_OFF + (hh + 5) * PADC + ww + 5;
        gst(ap, gld(ap) + ev[cb] * inv);
      }
#pragma unroll
      for (int cc = 0; cc < 8; cc++) {
        float p = 0.f;
#pragma unroll
        for (int j = 0; j < 8; j++) p += ev[j] * cnnS[cc * 4096 + j * 512 + tid];
#pragma unroll
        for (int off = 32; off; off >>= 1) p += __shfl_xor(p, off, 64);
        if ((tid & 63) == 0) redC[(tid >> 6) * 8 + cc] = p;
      }
      __syncthreads();
      if (tid < 8) {
        float cv = 0.f;
#pragma unroll
        for (int w2 = 0; w2 < 8; w2++) cv += redC[w2 * 8 + tid];
        gst(ws + CTXV_OFF + c0 + tid, cv * inv);
      }
      __syncthreads();
      if (tid == 0) rel_store(&flags[(CTX0 + cb) * 16], t + 1);
    }

  } else if (bid == MONO) {
    // ================= MONO: h, state, prob, argmax, h1 =================
    float* wst  = S;             // [256][128]
    float* mh   = S + 32768;     // 256
    float* mst  = S + 33024;     // 128
    float* sval = S + 33152;     // 512
    int*   sidx = (int*)(S + 33664);
    int*   mwp  = (int*)(S + 34176);
    int*   mwn  = (int*)(S + 34177);
    for (int i = tid; i < 256 * 128; i += 512) wst[i] = ws[WST_OFF + i];
    if (tid == 0) mwp[0] = 1;
    __syncthreads();

#pragma unroll 1
    for (int t = 0; t < T_STEPS; t++) {
      const int par = t & 1;
      if (tid < 128) pollf(&flags[tid * 16], t + 1);
      __syncthreads();
      if (tid < 8) rel_store(&afr[tid * 16], t + 1);
      if (tid < 8) pollf(&gfr[(tid * 8 + 7) * 16], t + 1);
      __syncthreads();
      if (tid < 256) {
        float g0 = bih_out[tid], g1 = bih_out[256 + tid], g2 = bih_out[512 + tid];
#pragma unroll
        for (int j = 0; j < 8; j++) {
          const float* gs = ws + GS_OFF + j * 768;
          g0 += gld(gs + tid);
          g1 += gld(gs + 256 + tid);
          g2 += gld(gs + 512 + tid);
        }
        const float* gh = ws + GHOV_OFF + par * 768;
        float o0 = gld(gh + tid), o1 = gld(gh + 256 + tid), o2 = gld(gh + 512 + tid);
        float h1v = gld(ws + H1V_OFF + par * 256 + tid);
        float r = sigmoidf_(g0 + o0);
        float z = sigmoidf_(g1 + o1);
        float n = tanhf(g2 + r * o2);
        mh[tid] = (1.f - z) * n + z * h1v;
      }
      __syncthreads();
      if (tid < 128) {
        float s = bs_[tid] + bc_[tid] + ws[SE_OFF + mwp[0] * 128 + tid];
#pragma unroll
        for (int j = 0; j < 8; j++) s += gld(ws + GPS_OFF + j * 128 + tid);
        const float* wt = wst + tid;
#pragma unroll 8
        for (int k = 0; k < 256; k++) s += mh[k] * wt[k * 128];
        mst[tid] = s;
      }
      __syncthreads();
      {
        float best = -3.4e38f;
        if (tid < V_DIM) {
          float p2 = bv_[tid];
          const float* wt = ws + WVT_OFF + tid;
#pragma unroll 8
          for (int k = 0; k < 128; k++) p2 += mst[k] * wt[k * V_DIM];
          out[t * V_DIM + tid] = p2;
          best = p2;
        }
        sval[tid] = best;
        sidx[tid] = tid;
        __syncthreads();
        for (int m = 256; m >= 1; m >>= 1) {
          if (tid < m) {
            float ov = sval[tid + m];
            int oi = sidx[tid + m];
            if (ov > sval[tid] || (ov == sval[tid] && oi < sidx[tid])) {
              sval[tid] = ov;
              sidx[tid] = oi;
            }
          }
          __syncthreads();
        }
        if (tid == 0) mwn[0] = sidx[0];
        __syncthreads();
      }
      if (tid < 16) pollf(&flags[(224 + tid) * 16], t + 1);
      __syncthreads();
      if (tid < 256) {
        const float* gi = ws + GI_OFF + mwn[0] * 768;
        float n0 = gld(ws + GHNV_OFF + tid);
        float n1 = gld(ws + GHNV_OFF + 256 + tid);
        float n2 = gld(ws + GHNV_OFF + 512 + tid);
        float r = sigmoidf_(gi[tid] + n0);
        float z = sigmoidf_(gi[256 + tid] + n1);
        float n = tanhf(gi[512 + tid] + r * n2);
        gst(ws + H1V_OFF + ((t + 1) & 1) * 256 + tid, (1.f - z) * n + z * mh[tid]);
      }
      __syncthreads();
      if (tid < 8) rel_store(&h1f[tid * 16], t + 1);
      if (tid == 0) mwp[0] = mwn[0];
      __syncthreads();
    }
    if (tid < 8) rel_store(&donef[tid * 16], 1);

  } else if (bid < TAIL0) {
    // ================= REDUCER j: gio/psc partial dots from CTXV =================
    const int j = bid - RED0;
    const int lo = j * 11, hi = (j == 7) ? 86 : (lo + 11);
    const int c0 = lo * 8, c1 = (hi * 8 < C_DIM) ? hi * 8 : C_DIM;
    float* cvS = S;  // up to 88
#pragma unroll 1
    for (int t = 0; t < T_STEPS; t++) {
      if (tid < hi - lo) pollf(&flags[(CTX0 + lo + tid) * 16], t + 1);
      __syncthreads();
      if (j == 0 && tid < 8) rel_store(&af2r[tid * 16], t + 1);
      if (tid < c1 - c0) cvS[tid] = gld(ws + CTXV_OFF + c0 + tid);
      __syncthreads();
      for (int m = tid; m < 768; m += 512) {
        float s = 0.f;
        for (int c = c0; c < c1; c++) s += cvS[c - c0] * ws[WIHTOUT_OFF + c * 768 + m];
        gst(ws + GS_OFF + j * 768 + m, s);
      }
      if (tid < 128) {
        float s = 0.f;
        for (int c = c0; c < c1; c++) s += cvS[c - c0] * ws[WCT_OFF + c * 128 + tid];
        gst(ws + GPS_OFF + j * 128 + tid, s);
      }
      __syncthreads();
      if (tid < 8) rel_store(&gfr[(j * 8 + tid) * 16], t + 1);
    }

  } else if (bid < HEAT0) {
    // ================= TAIL s (bank-conflict-free interleaved dots) =================
    const int s = bid - TAIL0;
    float* whinS = S;            // [48][264]
    float* whoS  = S + 12672;    // [48][264]
    float* wqS   = S + 25344;    // [32][264]
    float* hS    = S + 33792;    // 256
    float* h1S   = S + 34048;    // 256
    for (int i = tid; i < 48 * 256; i += 512) whinS[(i >> 8) * 264 + (i & 255)] = Whh_in[s * 12288 + i];
    for (int i = tid; i < 48 * 256; i += 512) whoS[(i >> 8) * 264 + (i & 255)] = Whh_out[s * 12288 + i];
    for (int i = tid; i < 32 * 256; i += 512) wqS[(i >> 8) * 264 + (i & 255)] = Wq[s * 8192 + i];
    __syncthreads();

#pragma unroll 1
    for (int t = 0; t < T_STEPS; t++) {
      const int par = t & 1;
      if (tid < 8) pollf(&gfr[(tid * 8 + (s & 7)) * 16], t + 1);
      __syncthreads();
      if (tid < 256) {
        float g0 = bih_out[tid], g1 = bih_out[256 + tid], g2 = bih_out[512 + tid];
#pragma unroll
        for (int j = 0; j < 8; j++) {
          const float* gs = ws + GS_OFF + j * 768;
          g0 += gld(gs + tid);
          g1 += gld(gs + 256 + tid);
          g2 += gld(gs + 512 + tid);
        }
        const float* gh = ws + GHOV_OFF + par * 768;
        float o0 = gld(gh + tid), o1 = gld(gh + 256 + tid), o2 = gld(gh + 512 + tid);
        float h1v = gld(ws + H1V_OFF + par * 256 + tid);
        float r = sigmoidf_(g0 + o0);
        float z = sigmoidf_(g1 + o1);
        float n = tanhf(g2 + r * o2);
        hS[tid] = (1.f - z) * n + z * h1v;
      }
      __syncthreads();
      // ghn slice (interleaved k: lane l reads k = j*32 + l*4)
      {
        int r = tid >> 3, l = tid & 7;
        if (r < 48) {
          int m = s * 48 + r;
          float sm = 0.f;
#pragma unroll
          for (int jj = 0; jj < 8; jj++) {
            float4 w4 = *(const float4*)&whinS[r * 264 + jj * 32 + l * 4];
            float4 h4 = *(const float4*)&hS[jj * 32 + l * 4];
            sm += w4.x * h4.x + w4.y * h4.y + w4.z * h4.z + w4.w * h4.w;
          }
#pragma unroll
          for (int off = 4; off; off >>= 1) sm += __shfl_xor(sm, off, 8);
          if (l == 0) gst(ws + GHNV_OFF + m, sm + bhh_in[m]);
        }
      }
      __syncthreads();
      if (tid == 0) rel_store(&flags[(224 + s) * 16], t + 1);
      if (tid == 0) pollf(&h1f[(s & 7) * 16], t + 1);
      __syncthreads();
      if (tid < 256) h1S[tid] = gld(ws + H1V_OFF + ((t + 1) & 1) * 256 + tid);
      __syncthreads();
      // gho(t+1) slice
      {
        int r = tid >> 3, l = tid & 7;
        if (r < 48) {
          int m = s * 48 + r;
          float sm = 0.f;
#pragma unroll
          for (int jj = 0; jj < 8; jj++) {
            float4 w4 = *(const float4*)&whoS[r * 264 + jj * 32 + l * 4];
            float4 h4 = *(const float4*)&h1S[jj * 32 + l * 4];
            sm += w4.x * h4.x + w4.y * h4.y + w4.z * h4.z + w4.w * h4.w;
          }
#pragma unroll
          for (int off = 4; off; off >>= 1) sm += __shfl_xor(sm, off, 8);
          if (l == 0) gst(ws + GHOV_OFF + ((t + 1) & 1) * 768 + m, sm + bhh_out[m]);
        }
      }
      // q(t+1) slice
      {
        int ap = tid >> 4, l = tid & 15;
        int a = s * 32 + ap;
        float sm = 0.f;
#pragma unroll
        for (int jj = 0; jj < 4; jj++) {
          float4 w4 = *(const float4*)&wqS[ap * 264 + jj * 64 + l * 4];
          float4 h4 = *(const float4*)&h1S[jj * 64 + l * 4];
          sm += w4.x * h4.x + w4.y * h4.y + w4.z * h4.z + w4.w * h4.w;
        }
#pragma unroll
        for (int off = 8; off; off >>= 1) sm += __shfl_xor(sm, off, 16);
        if (l == 0) gst(ws + QV_OFF + a, sm);
      }
      __syncthreads();
      if (tid < 8) rel_store(&tqr[(s * 8 + tid) * 16], t + 2);
    }

  } else {
    // ================= HEATER =================
    volatile int* hstop = (volatile int*)(S + 100);
    if (tid == 0) *hstop = 0;
    __syncthreads();
    if (tid < 256) {
      float a0 = 1.f + (float)tid, a1 = 2.f, a2 = 3.f, a3 = 4.f;
      const float b = 0.9999f, c = 1e-7f;
      while (*hstop == 0) {
#pragma unroll
        for (int i = 0; i < 16; i++) {
          a0 = __builtin_fmaf(a0, b, c);
          a1 = __builtin_fmaf(a1, b, c);
          a2 = __builtin_fmaf(a2, b, c);
          a3 = __builtin_fmaf(a3, b, c);
        }
        if (tid == 0 &&
            __hip_atomic_load(&donef[(bid & 7) * 16], __ATOMIC_RELAXED,
                              __HIP_MEMORY_SCOPE_AGENT) != 0)
          *hstop = 1;
      }
      asm volatile("" :: "v"(a0), "v"(a1), "v"(a2), "v"(a3));
    }
  }
}

// ---------------- host ----------------

extern "C" void kernel_launch(void* const* d_in, const int* in_sizes, int n_in,
                              void* d_out, int out_size, void* d_ws, size_t ws_size,
                              hipStream_t stream) {
  (void)in_sizes; (void)n_in; (void)out_size; (void)ws_size;
  const float* cnn      = (const float*)d_in[0];
  const float* imask    = (const float*)d_in[1];
  const float* emb_tab  = (const float*)d_in[2];
  const float* W_init   = (const float*)d_in[3];
  const float* b_init   = (const float*)d_in[4];
  const float* Wih_in   = (const float*)d_in[5];
  const float* Whh_in   = (const float*)d_in[6];
  const float* bih_in   = (const float*)d_in[7];
  const float* bhh_in   = (const float*)d_in[8];
  const float* Wih_out  = (const float*)d_in[9];
  const float* Whh_out  = (const float*)d_in[10];
  const float* bih_out  = (const float*)d_in[11];
  const float* bhh_out  = (const float*)d_in[12];
  const float* Wq       = (const float*)d_in[13];
  const float* bq       = (const float*)d_in[14];
  const float* Wproj    = (const float*)d_in[15];
  const float* bproj    = (const float*)d_in[16];
  const float* convk    = (const float*)d_in[17];
  const float* Wcov     = (const float*)d_in[18];
  const float* wa       = (const float*)d_in[19];
  const float* ba       = (const float*)d_in[20];
  const float* Ws_      = (const float*)d_in[21];
  const float* bs_      = (const float*)d_in[22];
  const float* We_      = (const float*)d_in[23];
  const float* be_      = (const float*)d_in[24];
  const float* Wc_      = (const float*)d_in[25];
  const float* bc_      = (const float*)d_in[26];
  const float* Wv_      = (const float*)d_in[27];
  const float* bv_      = (const float*)d_in[28];
  float* ws  = (float*)d_ws;
  float* out = (float*)d_out;

  k_init<<<1, 256, 0, stream>>>(imask, ws);
  k_avg<<<C_DIM, 256, 0, stream>>>(cnn, ws);
  k_h0<<<1, 256, 0, stream>>>(W_init, b_init, ws);
  k_km<<<121, 512, 0, stream>>>(convk, Wcov, ws);
  k_ct<<<dim3(HW / 128, A_DIM / 64), 256, 0, stream>>>(cnn, Wproj, bproj, ws);
  k_gi<<<V_DIM, 256, 0, stream>>>(emb_tab, Wih_in, bih_in, ws);
  k_se<<<V_DIM, 128, 0, stream>>>(emb_tab, We_, be_, ws);
  k_tr<<<512, 256, 0, stream>>>(Wih_out, ws + WIHTOUT_OFF, 768, 684);
  k_tr<<<512, 256, 0, stream>>>(Wc_, ws + WCT_OFF, 128, 684);
  k_tr<<<512, 256, 0, stream>>>(Ws_, ws + WST_OFF, 128, 256);
  k_tr<<<512, 256, 0, stream>>>(Wv_, ws + WVT_OFF, 415, 128);
  k_pre0<<<16, 512, 0, stream>>>(Whh_in, bhh_in, ws);
  k_pre1<<<16, 512, 0, stream>>>(Wq, Whh_out, bhh_out, ws);
  k_go<<<1, 256, 0, stream>>>(ws);

  k_steps<<<NGRID, 512, 0, stream>>>(cnn, Whh_in, Whh_out, Wq, bq, wa, ba,
                                     bih_out, bhh_out, bhh_in, bs_, bc_, bv_, ws, out);
}

// Round 15
// 2929.730 us; speedup vs baseline: 1.3909x; 1.3909x over previous
//
#include <hip/hip_runtime.h>
#include <math.h>

#define HF 32
#define WF 128
#define HW 4096
#define C_DIM 684
#define H_DIM 256
#define A_DIM 512
#define V_DIM 415
#define PADR 42
#define PADC 144
#define T_STEPS 64

#define NERG 128
#define CTX0 128
#define NCTXB 86
#define MONO 214
#define RED0 215   // 8 reducers 215..222
#define TAIL0 223  // 16 tail 223..238
#define HEAT0 239  // 16 heaters 239..254
#define NGRID 255

// ---------------- workspace layout (float offsets) ----------------
constexpr int CT_OFF      = 0;                        // [4096][512]
constexpr int KMT_OFF     = CT_OFF + HW * A_DIM;      // [512][121]
constexpr int APAD_OFF    = KMT_OFF + 61952;          // [42][144] mutable
constexpr int MASK_OFF    = APAD_OFF + 6048;
constexpr int PART_OFF    = MASK_OFF + 4096;          // [4][4096] mutable
constexpr int AVG_OFF     = PART_OFF + 16384;         // 704
constexpr int H0_OFF      = AVG_OFF + 704;            // 256
constexpr int QV_OFF      = H0_OFF + 256;             // [512] mutable
constexpr int H1V_OFF     = QV_OFF + 512;             // [2][256] mutable
constexpr int GHOV_OFF    = H1V_OFF + 512;            // [2][768] mutable
constexpr int GHNV_OFF    = GHOV_OFF + 1536;          // [768] mutable
constexpr int GS_OFF      = GHNV_OFF + 768;           // [8][768] mutable
constexpr int GPS_OFF     = GS_OFF + 6144;            // [8][128] mutable
constexpr int MSUM_OFF    = GPS_OFF + 1024;           // 16
// ---- contiguous SYNC region (cleared by k_init in one loop) ----
constexpr int FLAGS_OFF   = MSUM_OFF + 16;            // 256 lines x16: EF 0..127, CF 128..213, TF 224..239
constexpr int AFR_OFF     = FLAGS_OFF + 4096;         // 8 x16
constexpr int AF2R_OFF    = AFR_OFF + 128;            // 8 x16
constexpr int H1F_OFF     = AF2R_OFF + 128;           // 8 x16
constexpr int DONE_OFF    = H1F_OFF + 128;            // 8 x16
constexpr int GFR_OFF     = DONE_OFF + 128;           // [8 j][8 r] x16 = 1024
constexpr int TQR_OFF     = GFR_OFF + 1024;           // [16 s][8 r] x16 = 2048
constexpr int SYNC_END    = TQR_OFF + 2048;           // 7680 ints from FLAGS_OFF
// ---- tables ----
constexpr int PGIO2_OFF   = SYNC_END;                 // [86][768] mutable
constexpr int PSC2_OFF    = PGIO2_OFF + NCTXB * 768;  // [86][128] mutable
constexpr int GI_OFF      = PSC2_OFF + NCTXB * 128;   // [415][768]
constexpr int SE_OFF      = GI_OFF + V_DIM * 768;     // [415][128]
constexpr int WIHTOUT_OFF = SE_OFF + V_DIM * 128;     // [684][768]
constexpr int WCT_OFF     = WIHTOUT_OFF + 684 * 768;  // [684][128]
constexpr int WST_OFF     = WCT_OFF + 684 * 128;      // [256][128]
constexpr int WVT_OFF     = WST_OFF + 256 * 128;      // [128][415]
constexpr int WS_END      = WVT_OFF + 128 * V_DIM;

__device__ __forceinline__ float sigmoidf_(float x) { return 1.f / (1.f + expf(-x)); }
__device__ __forceinline__ float ftanh(float x) {
  float e = __expf(2.f * x);
  return 1.f - 2.f / (e + 1.f);
}

__device__ __forceinline__ float gld(const float* p) {
  int v = __hip_atomic_load((const int*)p, __ATOMIC_RELAXED, __HIP_MEMORY_SCOPE_AGENT);
  return __int_as_float(v);
}
__device__ __forceinline__ void gst(float* p, float x) {
  __hip_atomic_store((int*)p, __float_as_int(x), __ATOMIC_RELAXED, __HIP_MEMORY_SCOPE_AGENT);
}
__device__ __forceinline__ void pollf(int* p, int ph) {
  int it = 0;
  while (__hip_atomic_load(p, __ATOMIC_RELAXED, __HIP_MEMORY_SCOPE_AGENT) < ph) {
    if (it < 4) __builtin_amdgcn_s_sleep(1);
    else if (it < 16) __builtin_amdgcn_s_sleep(4);
    else __builtin_amdgcn_s_sleep(8);
    ++it;
  }
  asm volatile("" ::: "memory");
}
__device__ __forceinline__ void rel_store(int* p, int v) {
  __hip_atomic_store(p, v, __ATOMIC_RELEASE, __HIP_MEMORY_SCOPE_AGENT);
}

// ---------------- precompute ----------------

__global__ void k_init(const float* __restrict__ imask, float* ws) {
  __shared__ float red[4];
  int tid = threadIdx.x;
  float s = 0.f;
  for (int i = tid; i < HW; i += 256) {
    int h = i >> 7, w = i & 127;
    float m = imask[h * 16 * 2048 + w * 16];
    ws[MASK_OFF + i] = m;
    s += m;
  }
  for (int i = tid; i < PADR * PADC; i += 256) ws[APAD_OFF + i] = 0.f;
  int* sync = (int*)(ws + FLAGS_OFF);
  for (int i = tid; i < 7680; i += 256) sync[i] = 0;  // FULL sync-region reset
#pragma unroll
  for (int off = 32; off; off >>= 1) s += __shfl_xor(s, off, 64);
  if ((tid & 63) == 0) red[tid >> 6] = s;
  __syncthreads();
  if (tid == 0) ws[MSUM_OFF] = red[0] + red[1] + red[2] + red[3];
}

__global__ void k_avg(const float* __restrict__ cnn, float* ws) {
  __shared__ float red[4];
  int c = blockIdx.x, tid = threadIdx.x;
  const float* row = cnn + c * HW;
  float s = 0.f;
  for (int i = tid; i < HW; i += 256) s += ws[MASK_OFF + i] * row[i];
#pragma unroll
  for (int off = 32; off; off >>= 1) s += __shfl_xor(s, off, 64);
  if ((tid & 63) == 0) red[tid >> 6] = s;
  __syncthreads();
  if (tid == 0) ws[AVG_OFF + c] = (red[0] + red[1] + red[2] + red[3]) / ws[MSUM_OFF];
}

__global__ void k_h0(const float* __restrict__ W_init, const float* __restrict__ b_init, float* ws) {
  __shared__ float a_s[C_DIM];
  int tid = threadIdx.x;
  for (int i = tid; i < C_DIM; i += 256) a_s[i] = ws[AVG_OFF + i];
  __syncthreads();
  const float* wr = W_init + tid * C_DIM;
  float s = b_init[tid];
  for (int k = 0; k < C_DIM; k++) s += a_s[k] * wr[k];
  ws[H0_OFF + tid] = tanhf(s);
}

__global__ __launch_bounds__(512) void k_km(const float* __restrict__ convk,
                                            const float* __restrict__ Wcov, float* ws) {
  __shared__ float kt[256];
  int t = blockIdx.x, a = threadIdx.x;
  if (a < 256) kt[a] = convk[a * 121 + t];
  __syncthreads();
  const float* wr = Wcov + a * 256;
  float s = 0.f;
  for (int c = 0; c < 256; c++) s += kt[c] * wr[c];
  ws[KMT_OFF + a * 121 + t] = s;
}

__global__ void k_ct(const float* __restrict__ cnn, const float* __restrict__ Wproj,
                     const float* __restrict__ bproj, float* ws) {
  __shared__ float As[8][128];
  __shared__ float Bs[8][64];
  int hw0 = blockIdx.x * 128;
  int a0 = blockIdx.y * 64;
  int tid = threadIdx.x;
  int tx = tid & 15, ty = tid >> 4;
  float acc[8][4];
#pragma unroll
  for (int i = 0; i < 8; i++)
#pragma unroll
    for (int j = 0; j < 4; j++) acc[i][j] = 0.f;
  for (int c0 = 0; c0 < C_DIM; c0 += 8) {
    {
      int kk = tid >> 5;
      int m4 = (tid & 31) * 4;
      int c = c0 + kk;
      float4 v = make_float4(0.f, 0.f, 0.f, 0.f);
      if (c < C_DIM) v = *(const float4*)(cnn + c * HW + hw0 + m4);
      *(float4*)&As[kk][m4] = v;
    }
    {
      int n = tid & 63;
      int kk0 = (tid >> 6) * 2;
      const float* wr = Wproj + (a0 + n) * C_DIM + c0;
      Bs[kk0][n]     = (c0 + kk0 < C_DIM) ? wr[kk0] : 0.f;
      Bs[kk0 + 1][n] = (c0 + kk0 + 1 < C_DIM) ? wr[kk0 + 1] : 0.f;
    }
    __syncthreads();
#pragma unroll
    for (int kk = 0; kk < 8; kk++) {
      float a8[8], b4[4];
#pragma unroll
      for (int i = 0; i < 8; i++) a8[i] = As[kk][ty * 8 + i];
#pragma unroll
      for (int j = 0; j < 4; j++) b4[j] = Bs[kk][tx * 4 + j];
#pragma unroll
      for (int i = 0; i < 8; i++)
#pragma unroll
        for (int j = 0; j < 4; j++) acc[i][j] += a8[i] * b4[j];
    }
    __syncthreads();
  }
#pragma unroll
  for (int i = 0; i < 8; i++) {
    int hw = hw0 + ty * 8 + i;
#pragma unroll
    for (int j = 0; j < 4; j++) {
      int a = a0 + tx * 4 + j;
      ws[CT_OFF + hw * A_DIM + a] = acc[i][j] + bproj[a];
    }
  }
}

__global__ void k_gi(const float* __restrict__ emb_table, const float* __restrict__ Wih_in,
                     const float* __restrict__ bih_in, float* ws) {
  __shared__ float e_s[256];
  int v = blockIdx.x, tid = threadIdx.x;
  e_s[tid] = emb_table[v * 256 + tid];
  __syncthreads();
#pragma unroll
  for (int r = 0; r < 3; r++) {
    int m = r * 256 + tid;
    const float* wr = Wih_in + m * 256;
    float s = bih_in[m];
    for (int k = 0; k < 256; k++) s += e_s[k] * wr[k];
    ws[GI_OFF + v * 768 + m] = s;
  }
}

__global__ void k_se(const float* __restrict__ emb_table, const float* __restrict__ We,
                     const float* __restrict__ be, float* ws) {
  __shared__ float e_s[256];
  int v = blockIdx.x, tid = threadIdx.x;  // 128
  e_s[tid] = emb_table[v * 256 + tid];
  e_s[tid + 128] = emb_table[v * 256 + tid + 128];
  __syncthreads();
  const float* wr = We + tid * 256;
  float s = be[tid];
  for (int k = 0; k < 256; k++) s += e_s[k] * wr[k];
  ws[SE_OFF + v * 128 + tid] = s;
}

__global__ void k_tr(const float* __restrict__ in, float* __restrict__ out, int M, int Kd) {
  int total = M * Kd;
  for (int i = blockIdx.x * blockDim.x + threadIdx.x; i < total; i += gridDim.x * blockDim.x) {
    int m = i / Kd, k = i - m * Kd;
    out[k * M + m] = in[i];
  }
}

// bootstrap 1: h1(0) slices -> H1V slot0 (word = 1)
__global__ __launch_bounds__(512) void k_pre0(const float* __restrict__ Whh_in,
                                              const float* __restrict__ bhh_in, float* ws) {
  __shared__ float h0s[256];
  __shared__ float ghn48[48];
  const int s = blockIdx.x, tid = threadIdx.x;
  const int j0 = s * 16;
  if (tid < 256) h0s[tid] = ws[H0_OFF + tid];
  __syncthreads();
  {
    int r = tid >> 3, l = tid & 7;
    if (r < 48) {
      int mg = (r >> 4) * 256 + j0 + (r & 15);
      const float* wr = Whh_in + mg * 256 + l * 32;
      float sm = 0.f;
#pragma unroll
      for (int k = 0; k < 32; k++) sm += h0s[l * 32 + k] * wr[k];
#pragma unroll
      for (int off = 4; off; off >>= 1) sm += __shfl_xor(sm, off, 8);
      if (l == 0) ghn48[r] = sm + bhh_in[mg];
    }
  }
  __syncthreads();
  if (tid < 16) {
    int j = j0 + tid;
    const float* gi = ws + GI_OFF + 1 * 768;
    float r = sigmoidf_(gi[j] + ghn48[tid]);
    float z = sigmoidf_(gi[256 + j] + ghn48[16 + tid]);
    float n = tanhf(gi[512 + j] + r * ghn48[32 + tid]);
    gst(ws + H1V_OFF + j, (1.f - z) * n + z * h0s[j]);  // slot 0
  }
}

// bootstrap 2: q(0) and gho(0) slices from H1V slot0
__global__ __launch_bounds__(512) void k_pre1(const float* __restrict__ Wq,
                                              const float* __restrict__ Whh_out,
                                              const float* __restrict__ bhh_out, float* ws) {
  __shared__ float h1s[256];
  const int s = blockIdx.x, tid = threadIdx.x;
  if (tid < 256) h1s[tid] = gld(ws + H1V_OFF + tid);
  __syncthreads();
  {
    int ap = tid >> 4, l = tid & 15;
    int a = s * 32 + ap;
    const float* wr = Wq + a * 256 + l * 16;
    float sm = 0.f;
#pragma unroll
    for (int k = 0; k < 16; k++) sm += h1s[l * 16 + k] * wr[k];
#pragma unroll
    for (int off = 8; off; off >>= 1) sm += __shfl_xor(sm, off, 16);
    if (l == 0) gst(ws + QV_OFF + a, sm);
  }
  {
    int r = tid >> 3, l = tid & 7;
    if (r < 48) {
      int m = s * 48 + r;
      const float* wr = Whh_out + m * 256 + l * 32;
      float sm = 0.f;
#pragma unroll
      for (int k = 0; k < 32; k++) sm += h1s[l * 32 + k] * wr[k];
#pragma unroll
      for (int off = 4; off; off >>= 1) sm += __shfl_xor(sm, off, 8);
      if (l == 0) gst(ws + GHOV_OFF + m, sm + bhh_out[m]);  // slot 0
    }
  }
}

__global__ void k_go(float* ws) {
  int tid = threadIdx.x;
  if (tid < 128) ((int*)(ws + TQR_OFF))[tid * 16] = 1;  // q(0) ready
}

// ---------------- persistent kernel ----------------
// r13 structure (ctx computes gio/psc partials; reducers do cheap 11-way sums)
// + r14's bank-conflict-free tail (264-padded, interleaved-k float4 dots).

__global__ __launch_bounds__(512) void k_steps(
    const float* __restrict__ cnn, const float* __restrict__ Whh_in,
    const float* __restrict__ Whh_out, const float* __restrict__ Wq,
    const float* __restrict__ bq, const float* __restrict__ wa, const float* __restrict__ ba,
    const float* __restrict__ bih_out, const float* __restrict__ bhh_out,
    const float* __restrict__ bhh_in,
    const float* __restrict__ bs_, const float* __restrict__ bc_, const float* __restrict__ bv_,
    float* ws, float* __restrict__ out) {
  __shared__ __align__(16) float S[40016];

  const int bid = blockIdx.x, tid = threadIdx.x;
  int* flags = (int*)(ws + FLAGS_OFF);
  int* afr   = (int*)(ws + AFR_OFF);
  int* af2r  = (int*)(ws + AF2R_OFF);
  int* h1f   = (int*)(ws + H1F_OFF);
  int* donef = (int*)(ws + DONE_OFF);
  int* gfr   = (int*)(ws + GFR_OFF);
  int* tqr   = (int*)(ws + TQR_OFF);

  if (bid < NERG) {
    // ================= ENERGY =================
    const int h_row = bid >> 2, aq = bid & 3, a0 = aq * 128;
    const int al = tid & 127, hslot = tid >> 7;
    float* km    = S;          // [128][132]
    float* ct    = S + 16896;  // [128][128]
    float* patch = S + 33280;  // [11][144]
    float* maskv = S + 34864;
    float* redE  = S + 34992;
    for (int i = tid; i < 128 * 132; i += 512) {
      int a = i / 132, j = i - a * 132;
      int dy = j / 12, dx = j - dy * 12;
      km[i] = (dx < 11) ? ws[KMT_OFF + (a0 + a) * 121 + dy * 11 + dx] : 0.f;
    }
    for (int i = tid; i < 128 * 128; i += 512) {
      int w = i >> 7, aa = i & 127;
      ct[i] = ws[CT_OFF + (h_row * 128 + w) * 512 + a0 + aa];
    }
    if (tid < 128) maskv[tid] = ws[MASK_OFF + h_row * 128 + tid];
    const float bq_a = bq[a0 + al], wa_a = wa[a0 + al], ba0 = ba[0];
    __syncthreads();

#pragma unroll 1
    for (int t = 0; t < T_STEPS; t++) {
      if (tid == 0) pollf(&af2r[(bid & 7) * 16], t);
      __syncthreads();
      for (int i = tid; i < 11 * 138; i += 512) {
        int r = i / 138, c = i - r * 138;
        patch[r * 144 + c] = gld(ws + APAD_OFF + (h_row + r) * PADC + c);
      }
      __syncthreads();
      float acc[2][16];
#pragma unroll
      for (int p = 0; p < 2; p++)
#pragma unroll
        for (int i = 0; i < 16; i++) acc[p][i] = 0.f;
      const int wbase0 = hslot * 32;
#pragma unroll 1
      for (int dy = 0; dy < 11; dy++) {
        float kv[12];
        {
          const float* kb = &km[al * 132 + dy * 12];
          *(float4*)&kv[0] = *(const float4*)&kb[0];
          *(float4*)&kv[4] = *(const float4*)&kb[4];
          *(float4*)&kv[8] = *(const float4*)&kb[8];
        }
#pragma unroll
        for (int p = 0; p < 2; p++) {
          float row[28];
          const float* pr = &patch[dy * 144 + wbase0 + p * 16];
#pragma unroll
          for (int i = 0; i < 7; i++) *(float4*)&row[i * 4] = *(const float4*)&pr[i * 4];
#pragma unroll
          for (int dx = 0; dx < 11; dx++)
#pragma unroll
            for (int wi = 0; wi < 16; wi++) acc[p][wi] += kv[dx] * row[wi + dx];
        }
      }
      // q gate
      if (tid < 16) pollf(&tqr[(tid * 8 + (bid & 7)) * 16], t + 1);
      __syncthreads();
      float qa = bq_a + gld(ws + QV_OFF + a0 + al);
#pragma unroll 1
      for (int p = 0; p < 2; p++) {
        const int wbase = wbase0 + p * 16;
#pragma unroll
        for (int wi = 0; wi < 16; wi++) {
          float x = acc[p][wi] + qa + ct[(wbase + wi) * 128 + al];
          float v = ftanh(x) * wa_a;
#pragma unroll
          for (int off = 32; off; off >>= 1) v += __shfl_xor(v, off, 64);
          if ((tid & 63) == 0) redE[(tid >> 6) * 16 + wi] = v;
        }
        __syncthreads();
        if (tid < 64) {
          int hs2 = tid >> 4, wi = tid & 15;
          int w = hs2 * 32 + p * 16 + wi;
          float e = redE[(hs2 * 2) * 16 + wi] + redE[(hs2 * 2 + 1) * 16 + wi];
          float val = (maskv[w] > 0.f) ? (e + (aq == 0 ? ba0 : 0.f)) : -2.5e8f;
          gst(ws + PART_OFF + aq * 4096 + h_row * 128 + w, val);
        }
        __syncthreads();
      }
      if (tid == 0) rel_store(&flags[bid * 16], t + 1);
    }

  } else if (bid < CTX0 + NCTXB) {
    // ================= CTX (r13: computes gio/psc partials) =================
    const int cb = bid - CTX0, c0 = cb * 8;
    float* cnnS = S;           // 32768
    float* wio  = S + 32768;   // 6144
    float* wct  = S + 38912;   // 1024
    float* redC = S + 39936;   // 64
    float* ctxv = S + 40000;   // 8
    float* invp = S + 40008;
    for (int i = tid; i < 8 * 4096; i += 512) {
      int c = c0 + (i >> 12);
      cnnS[i] = (c < C_DIM) ? cnn[c * 4096 + (i & 4095)] : 0.f;
    }
    for (int i = tid; i < 8 * 768; i += 512) {
      int c = c0 + i / 768;
      wio[i] = (c < C_DIM) ? ws[WIHTOUT_OFF + c * 768 + (i % 768)] : 0.f;
    }
    for (int i = tid; i < 8 * 128; i += 512) {
      int c = c0 + (i >> 7);
      wct[i] = (c < C_DIM) ? ws[WCT_OFF + c * 128 + (i & 127)] : 0.f;
    }
    __syncthreads();

#pragma unroll 1
    for (int t = 0; t < T_STEPS; t++) {
      if (tid == 0) pollf(&afr[(bid & 7) * 16], t + 1);
      __syncthreads();
      float ev[8];
      float ssum = 0.f;
#pragma unroll
      for (int j = 0; j < 8; j++) {
        int hw = j * 512 + tid;
        float e = gld(ws + PART_OFF + hw) + gld(ws + PART_OFF + 4096 + hw) +
                  gld(ws + PART_OFF + 8192 + hw) + gld(ws + PART_OFF + 12288 + hw);
        ev[j] = __expf(e);
        ssum += ev[j];
      }
#pragma unroll
      for (int off = 32; off; off >>= 1) ssum += __shfl_xor(ssum, off, 64);
      if ((tid & 63) == 0) redC[tid >> 6] = ssum;
      __syncthreads();
      if (tid == 0) {
        float s2 = 0.f;
#pragma unroll
        for (int i = 0; i < 8; i++) s2 += redC[i];
        invp[0] = 1.f / s2;
      }
      __syncthreads();
      float inv = invp[0];
      if (cb < 8) {
        int hw = cb * 512 + tid;
        int hh = hw >> 7, ww = hw & 127;
        float* ap = ws + APAD_OFF + (hh + 5) * PADC + ww + 5;
        gst(ap, gld(ap) + ev[cb] * inv);
      }
#pragma unroll
      for (int cc = 0; cc < 8; cc++) {
        float p = 0.f;
#pragma unroll
        for (int j = 0; j < 8; j++) p += ev[j] * cnnS[cc * 4096 + j * 512 + tid];
#pragma unroll
        for (int off = 32; off; off >>= 1) p += __shfl_xor(p, off, 64);
        if ((tid & 63) == 0) redC[(tid >> 6) * 8 + cc] = p;
      }
      __syncthreads();
      if (tid < 8) {
        float cv = 0.f;
#pragma unroll
        for (int w2 = 0; w2 < 8; w2++) cv += redC[w2 * 8 + tid];
        ctxv[tid] = cv * inv;
      }
      __syncthreads();
      for (int m = tid; m < 768; m += 512) {
        float s2 = 0.f;
#pragma unroll
        for (int cc = 0; cc < 8; cc++) s2 += ctxv[cc] * wio[cc * 768 + m];
        gst(ws + PGIO2_OFF + cb * 768 + m, s2);
      }
      if (tid < 128) {
        float s2 = 0.f;
#pragma unroll
        for (int cc = 0; cc < 8; cc++) s2 += ctxv[cc] * wct[cc * 128 + tid];
        gst(ws + PSC2_OFF + cb * 128 + tid, s2);
      }
      __syncthreads();
      if (tid == 0) rel_store(&flags[(CTX0 + cb) * 16], t + 1);
    }

  } else if (bid == MONO) {
    // ================= MONO: h, state, prob, argmax, h1 =================
    float* wst  = S;             // [256][128]
    float* mh   = S + 32768;     // 256
    float* mst  = S + 33024;     // 128
    float* sval = S + 33152;     // 512
    int*   sidx = (int*)(S + 33664);
    int*   mwp  = (int*)(S + 34176);
    int*   mwn  = (int*)(S + 34177);
    for (int i = tid; i < 256 * 128; i += 512) wst[i] = ws[WST_OFF + i];
    if (tid == 0) mwp[0] = 1;
    __syncthreads();

#pragma unroll 1
    for (int t = 0; t < T_STEPS; t++) {
      const int par = t & 1;
      if (tid < 128) pollf(&flags[tid * 16], t + 1);
      __syncthreads();
      if (tid < 8) rel_store(&afr[tid * 16], t + 1);
      if (tid < 8) pollf(&gfr[(tid * 8 + 7) * 16], t + 1);
      __syncthreads();
      if (tid < 256) {
        float g0 = bih_out[tid], g1 = bih_out[256 + tid], g2 = bih_out[512 + tid];
#pragma unroll
        for (int j = 0; j < 8; j++) {
          const float* gs = ws + GS_OFF + j * 768;
          g0 += gld(gs + tid);
          g1 += gld(gs + 256 + tid);
          g2 += gld(gs + 512 + tid);
        }
        const float* gh = ws + GHOV_OFF + par * 768;
        float o0 = gld(gh + tid), o1 = gld(gh + 256 + tid), o2 = gld(gh + 512 + tid);
        float h1v = gld(ws + H1V_OFF + par * 256 + tid);
        float r = sigmoidf_(g0 + o0);
        float z = sigmoidf_(g1 + o1);
        float n = tanhf(g2 + r * o2);
        mh[tid] = (1.f - z) * n + z * h1v;
      }
      __syncthreads();
      if (tid < 128) {
        float s = bs_[tid] + bc_[tid] + ws[SE_OFF + mwp[0] * 128 + tid];
#pragma unroll
        for (int j = 0; j < 8; j++) s += gld(ws + GPS_OFF + j * 128 + tid);
        const float* wt = wst + tid;
#pragma unroll 8
        for (int k = 0; k < 256; k++) s += mh[k] * wt[k * 128];
        mst[tid] = s;
      }
      __syncthreads();
      {
        float best = -3.4e38f;
        if (tid < V_DIM) {
          float p2 = bv_[tid];
          const float* wt = ws + WVT_OFF + tid;
#pragma unroll 8
          for (int k = 0; k < 128; k++) p2 += mst[k] * wt[k * V_DIM];
          out[t * V_DIM + tid] = p2;
          best = p2;
        }
        sval[tid] = best;
        sidx[tid] = tid;
        __syncthreads();
        for (int m = 256; m >= 1; m >>= 1) {
          if (tid < m) {
            float ov = sval[tid + m];
            int oi = sidx[tid + m];
            if (ov > sval[tid] || (ov == sval[tid] && oi < sidx[tid])) {
              sval[tid] = ov;
              sidx[tid] = oi;
            }
          }
          __syncthreads();
        }
        if (tid == 0) mwn[0] = sidx[0];
        __syncthreads();
      }
      if (tid < 16) pollf(&flags[(224 + tid) * 16], t + 1);
      __syncthreads();
      if (tid < 256) {
        const float* gi = ws + GI_OFF + mwn[0] * 768;
        float n0 = gld(ws + GHNV_OFF + tid);
        float n1 = gld(ws + GHNV_OFF + 256 + tid);
        float n2 = gld(ws + GHNV_OFF + 512 + tid);
        float r = sigmoidf_(gi[tid] + n0);
        float z = sigmoidf_(gi[256 + tid] + n1);
        float n = tanhf(gi[512 + tid] + r * n2);
        gst(ws + H1V_OFF + ((t + 1) & 1) * 256 + tid, (1.f - z) * n + z * mh[tid]);
      }
      __syncthreads();
      if (tid < 8) rel_store(&h1f[tid * 16], t + 1);
      if (tid == 0) mwp[0] = mwn[0];
      __syncthreads();
    }
    if (tid < 8) rel_store(&donef[tid * 16], 1);

  } else if (bid < TAIL0) {
    // ================= REDUCER j (r13: cheap 11-way sums) =================
    const int j = bid - RED0;
    const int lo = j * 11, hi = (j == 7) ? 86 : (lo + 11);
#pragma unroll 1
    for (int t = 0; t < T_STEPS; t++) {
      if (tid < hi - lo) pollf(&flags[(CTX0 + lo + tid) * 16], t + 1);
      __syncthreads();
      if (j == 0 && tid < 8) rel_store(&af2r[tid * 16], t + 1);
      for (int m = tid; m < 768; m += 512) {
        float s = 0.f;
        for (int cb = lo; cb < hi; cb++) s += gld(ws + PGIO2_OFF + cb * 768 + m);
        gst(ws + GS_OFF + j * 768 + m, s);
      }
      if (tid < 128) {
        float s = 0.f;
        for (int cb = lo; cb < hi; cb++) s += gld(ws + PSC2_OFF + cb * 128 + tid);
        gst(ws + GPS_OFF + j * 128 + tid, s);
      }
      __syncthreads();
      if (tid < 8) rel_store(&gfr[(j * 8 + tid) * 16], t + 1);
    }

  } else if (bid < HEAT0) {
    // ================= TAIL s (264-padded, interleaved-k, conflict-free) =================
    const int s = bid - TAIL0;
    float* whinS = S;            // [48][264]
    float* whoS  = S + 12672;    // [48][264]
    float* wqS   = S + 25344;    // [32][264]
    float* hS    = S + 33792;    // 256
    float* h1S   = S + 34048;    // 256
    for (int i = tid; i < 48 * 256; i += 512) whinS[(i >> 8) * 264 + (i & 255)] = Whh_in[s * 12288 + i];
    for (int i = tid; i < 48 * 256; i += 512) whoS[(i >> 8) * 264 + (i & 255)] = Whh_out[s * 12288 + i];
    for (int i = tid; i < 32 * 256; i += 512) wqS[(i >> 8) * 264 + (i & 255)] = Wq[s * 8192 + i];
    __syncthreads();

#pragma unroll 1
    for (int t = 0; t < T_STEPS; t++) {
      const int par = t & 1;
      if (tid < 8) pollf(&gfr[(tid * 8 + (s & 7)) * 16], t + 1);
      __syncthreads();
      if (tid < 256) {
        float g0 = bih_out[tid], g1 = bih_out[256 + tid], g2 = bih_out[512 + tid];
#pragma unroll
        for (int j = 0; j < 8; j++) {
          const float* gs = ws + GS_OFF + j * 768;
          g0 += gld(gs + tid);
          g1 += gld(gs + 256 + tid);
          g2 += gld(gs + 512 + tid);
        }
        const float* gh = ws + GHOV_OFF + par * 768;
        float o0 = gld(gh + tid), o1 = gld(gh + 256 + tid), o2 = gld(gh + 512 + tid);
        float h1v = gld(ws + H1V_OFF + par * 256 + tid);
        float r = sigmoidf_(g0 + o0);
        float z = sigmoidf_(g1 + o1);
        float n = tanhf(g2 + r * o2);
        hS[tid] = (1.f - z) * n + z * h1v;
      }
      __syncthreads();
      // ghn slice (interleaved k)
      {
        int r = tid >> 3, l = tid & 7;
        if (r < 48) {
          int m = s * 48 + r;
          float sm = 0.f;
#pragma unroll
          for (int jj = 0; jj < 8; jj++) {
            float4 w4 = *(const float4*)&whinS[r * 264 + jj * 32 + l * 4];
            float4 h4 = *(const float4*)&hS[jj * 32 + l * 4];
            sm += w4.x * h4.x + w4.y * h4.y + w4.z * h4.z + w4.w * h4.w;
          }
#pragma unroll
          for (int off = 4; off; off >>= 1) sm += __shfl_xor(sm, off, 8);
          if (l == 0) gst(ws + GHNV_OFF + m, sm + bhh_in[m]);
        }
      }
      __syncthreads();
      if (tid == 0) rel_store(&flags[(224 + s) * 16], t + 1);
      if (tid == 0) pollf(&h1f[(s & 7) * 16], t + 1);
      __syncthreads();
      if (tid < 256) h1S[tid] = gld(ws + H1V_OFF + ((t + 1) & 1) * 256 + tid);
      __syncthreads();
      // gho(t+1) slice
      {
        int r = tid >> 3, l = tid & 7;
        if (r < 48) {
          int m = s * 48 + r;
          float sm = 0.f;
#pragma unroll
          for (int jj = 0; jj < 8; jj++) {
            float4 w4 = *(const float4*)&whoS[r * 264 + jj * 32 + l * 4];
            float4 h4 = *(const float4*)&h1S[jj * 32 + l * 4];
            sm += w4.x * h4.x + w4.y * h4.y + w4.z * h4.z + w4.w * h4.w;
          }
#pragma unroll
          for (int off = 4; off; off >>= 1) sm += __shfl_xor(sm, off, 8);
          if (l == 0) gst(ws + GHOV_OFF + ((t + 1) & 1) * 768 + m, sm + bhh_out[m]);
        }
      }
      // q(t+1) slice
      {
        int ap = tid >> 4, l = tid & 15;
        int a = s * 32 + ap;
        float sm = 0.f;
#pragma unroll
        for (int jj = 0; jj < 4; jj++) {
          float4 w4 = *(const float4*)&wqS[ap * 264 + jj * 64 + l * 4];
          float4 h4 = *(const float4*)&h1S[jj * 64 + l * 4];
          sm += w4.x * h4.x + w4.y * h4.y + w4.z * h4.z + w4.w * h4.w;
        }
#pragma unroll
        for (int off = 8; off; off >>= 1) sm += __shfl_xor(sm, off, 16);
        if (l == 0) gst(ws + QV_OFF + a, sm);
      }
      __syncthreads();
      if (tid < 8) rel_store(&tqr[(s * 8 + tid) * 16], t + 2);
    }

  } else {
    // ================= HEATER =================
    volatile int* hstop = (volatile int*)(S + 100);
    if (tid == 0) *hstop = 0;
    __syncthreads();
    if (tid < 256) {
      float a0 = 1.f + (float)tid, a1 = 2.f, a2 = 3.f, a3 = 4.f;
      const float b = 0.9999f, c = 1e-7f;
      while (*hstop == 0) {
#pragma unroll
        for (int i = 0; i < 16; i++) {
          a0 = __builtin_fmaf(a0, b, c);
          a1 = __builtin_fmaf(a1, b, c);
          a2 = __builtin_fmaf(a2, b, c);
          a3 = __builtin_fmaf(a3, b, c);
        }
        if (tid == 0 &&
            __hip_atomic_load(&donef[(bid & 7) * 16], __ATOMIC_RELAXED,
                              __HIP_MEMORY_SCOPE_AGENT) != 0)
          *hstop = 1;
      }
      asm volatile("" :: "v"(a0), "v"(a1), "v"(a2), "v"(a3));
    }
  }
}

// ---------------- host ----------------

extern "C" void kernel_launch(void* const* d_in, const int* in_sizes, int n_in,
                              void* d_out, int out_size, void* d_ws, size_t ws_size,
                              hipStream_t stream) {
  (void)in_sizes; (void)n_in; (void)out_size; (void)ws_size;
  const float* cnn      = (const float*)d_in[0];
  const float* imask    = (const float*)d_in[1];
  const float* emb_tab  = (const float*)d_in[2];
  const float* W_init   = (const float*)d_in[3];
  const float* b_init   = (const float*)d_in[4];
  const float* Wih_in   = (const float*)d_in[5];
  const float* Whh_in   = (const float*)d_in[6];
  const float* bih_in   = (const float*)d_in[7];
  const float* bhh_in   = (const float*)d_in[8];
  const float* Wih_out  = (const float*)d_in[9];
  const float* Whh_out  = (const float*)d_in[10];
  const float* bih_out  = (const float*)d_in[11];
  const float* bhh_out  = (const float*)d_in[12];
  const float* Wq       = (const float*)d_in[13];
  const float* bq       = (const float*)d_in[14];
  const float* Wproj    = (const float*)d_in[15];
  const float* bproj    = (const float*)d_in[16];
  const float* convk    = (const float*)d_in[17];
  const float* Wcov     = (const float*)d_in[18];
  const float* wa       = (const float*)d_in[19];
  const float* ba       = (const float*)d_in[20];
  const float* Ws_      = (const float*)d_in[21];
  const float* bs_      = (const float*)d_in[22];
  const float* We_      = (const float*)d_in[23];
  const float* be_      = (const float*)d_in[24];
  const float* Wc_      = (const float*)d_in[25];
  const float* bc_      = (const float*)d_in[26];
  const float* Wv_      = (const float*)d_in[27];
  const float* bv_      = (const float*)d_in[28];
  float* ws  = (float*)d_ws;
  float* out = (float*)d_out;

  k_init<<<1, 256, 0, stream>>>(imask, ws);
  k_avg<<<C_DIM, 256, 0, stream>>>(cnn, ws);
  k_h0<<<1, 256, 0, stream>>>(W_init, b_init, ws);
  k_km<<<121, 512, 0, stream>>>(convk, Wcov, ws);
  k_ct<<<dim3(HW / 128, A_DIM / 64), 256, 0, stream>>>(cnn, Wproj, bproj, ws);
  k_gi<<<V_DIM, 256, 0, stream>>>(emb_tab, Wih_in, bih_in, ws);
  k_se<<<V_DIM, 128, 0, stream>>>(emb_tab, We_, be_, ws);
  k_tr<<<512, 256, 0, stream>>>(Wih_out, ws + WIHTOUT_OFF, 768, 684);
  k_tr<<<512, 256, 0, stream>>>(Wc_, ws + WCT_OFF, 128, 684);
  k_tr<<<512, 256, 0, stream>>>(Ws_, ws + WST_OFF, 128, 256);
  k_tr<<<512, 256, 0, stream>>>(Wv_, ws + WVT_OFF, 415, 128);
  k_pre0<<<16, 512, 0, stream>>>(Whh_in, bhh_in, ws);
  k_pre1<<<16, 512, 0, stream>>>(Wq, Whh_out, bhh_out, ws);
  k_go<<<1, 256, 0, stream>>>(ws);

  k_steps<<<NGRID, 512, 0, stream>>>(cnn, Whh_in, Whh_out, Wq, bq, wa, ba,
                                     bih_out, bhh_out, bhh_in, bs_, bc_, bv_, ws, out);
}

// Round 16
// 2750.283 us; speedup vs baseline: 1.4817x; 1.0652x over previous
//
#include <hip/hip_runtime.h>
#include <math.h>

#define HF 32
#define WF 128
#define HW 4096
#define C_DIM 684
#define H_DIM 256
#define A_DIM 512
#define V_DIM 415
#define PADR 42
#define PADC 144
#define T_STEPS 64

#define NERG 128
#define CTX0 128
#define NCTXB 86
#define MONO 214
#define TAIL0 215   // 16 tail 215..230
#define GIO0 231    // 16 gio 231..246
#define PSC0 247    // 4 psc 247..250
#define NGRID 251

// ---------------- workspace layout (float offsets) ----------------
constexpr int CT_OFF      = 0;                        // [4096][512]
constexpr int KMT_OFF     = CT_OFF + HW * A_DIM;      // [512][121]
constexpr int APAD_OFF    = KMT_OFF + 61952;          // [42][144] mutable
constexpr int MASK_OFF    = APAD_OFF + 6048;
constexpr int PART_OFF    = MASK_OFF + 4096;          // [4][4096] mutable
constexpr int AVG_OFF     = PART_OFF + 16384;         // 704
constexpr int H0_OFF      = AVG_OFF + 704;            // 256
constexpr int QV_OFF      = H0_OFF + 256;             // [512] mutable
constexpr int H1V_OFF     = QV_OFF + 512;             // [2][256] mutable
constexpr int GHOV_OFF    = H1V_OFF + 512;            // [2][768] mutable
constexpr int GHNV_OFF    = GHOV_OFF + 1536;          // [768] mutable
constexpr int GIOV_OFF    = GHNV_OFF + 768;           // [768] mutable (bias included)
constexpr int PSCV_OFF    = GIOV_OFF + 768;           // [128] mutable
constexpr int CTXV_OFF    = PSCV_OFF + 128;           // [704] mutable
constexpr int MSUM_OFF    = CTXV_OFF + 704;           // 16
// ---- contiguous SYNC region ----
constexpr int FLAGS_OFF   = MSUM_OFF + 16;            // 256 lines x16:
// EF 0..127, CF 128..213, TF 214..229, GF 230..245, PSCF 246..249
constexpr int AFR_OFF     = FLAGS_OFF + 4096;         // 8 x16
constexpr int CR_OFF      = AFR_OFF + 128;            // 8 x16 (ctx-done; gates E conv + gio/psc)
constexpr int H1F_OFF     = CR_OFF + 128;             // 8 x16
constexpr int TQR_OFF     = H1F_OFF + 128;            // [16 s][8 r] x16 = 2048
constexpr int SYNC_INTS   = 4096 + 128 + 128 + 128 + 2048;  // 6528
constexpr int SYNC_END    = FLAGS_OFF + SYNC_INTS;
// ---- tables ----
constexpr int GI_OFF      = SYNC_END;                 // [415][768]
constexpr int SE_OFF      = GI_OFF + V_DIM * 768;     // [415][128]
constexpr int WST_OFF     = SE_OFF + V_DIM * 128;     // [256][128]
constexpr int WVT_OFF     = WST_OFF + 256 * 128;      // [128][415]
constexpr int WS_END      = WVT_OFF + 128 * V_DIM;

__device__ __forceinline__ float sigmoidf_(float x) { return 1.f / (1.f + expf(-x)); }
__device__ __forceinline__ float ftanh(float x) {
  float e = __expf(2.f * x);
  return 1.f - 2.f / (e + 1.f);
}

__device__ __forceinline__ float gld(const float* p) {
  int v = __hip_atomic_load((const int*)p, __ATOMIC_RELAXED, __HIP_MEMORY_SCOPE_AGENT);
  return __int_as_float(v);
}
__device__ __forceinline__ void gst(float* p, float x) {
  __hip_atomic_store((int*)p, __float_as_int(x), __ATOMIC_RELAXED, __HIP_MEMORY_SCOPE_AGENT);
}
__device__ __forceinline__ void pollf(int* p, int ph) {
  int it = 0;
  while (__hip_atomic_load(p, __ATOMIC_RELAXED, __HIP_MEMORY_SCOPE_AGENT) < ph) {
    if (it < 4) __builtin_amdgcn_s_sleep(1);
    else if (it < 16) __builtin_amdgcn_s_sleep(4);
    else __builtin_amdgcn_s_sleep(8);
    ++it;
  }
  asm volatile("" ::: "memory");
}
__device__ __forceinline__ void rel_store(int* p, int v) {
  __hip_atomic_store(p, v, __ATOMIC_RELEASE, __HIP_MEMORY_SCOPE_AGENT);
}

// ---------------- precompute ----------------

__global__ void k_init(const float* __restrict__ imask, float* ws) {
  __shared__ float red[4];
  int tid = threadIdx.x;
  float s = 0.f;
  for (int i = tid; i < HW; i += 256) {
    int h = i >> 7, w = i & 127;
    float m = imask[h * 16 * 2048 + w * 16];
    ws[MASK_OFF + i] = m;
    s += m;
  }
  for (int i = tid; i < PADR * PADC; i += 256) ws[APAD_OFF + i] = 0.f;
  int* sync = (int*)(ws + FLAGS_OFF);
  for (int i = tid; i < SYNC_INTS; i += 256) sync[i] = 0;
#pragma unroll
  for (int off = 32; off; off >>= 1) s += __shfl_xor(s, off, 64);
  if ((tid & 63) == 0) red[tid >> 6] = s;
  __syncthreads();
  if (tid == 0) ws[MSUM_OFF] = red[0] + red[1] + red[2] + red[3];
}

__global__ void k_avg(const float* __restrict__ cnn, float* ws) {
  __shared__ float red[4];
  int c = blockIdx.x, tid = threadIdx.x;
  const float* row = cnn + c * HW;
  float s = 0.f;
  for (int i = tid; i < HW; i += 256) s += ws[MASK_OFF + i] * row[i];
#pragma unroll
  for (int off = 32; off; off >>= 1) s += __shfl_xor(s, off, 64);
  if ((tid & 63) == 0) red[tid >> 6] = s;
  __syncthreads();
  if (tid == 0) ws[AVG_OFF + c] = (red[0] + red[1] + red[2] + red[3]) / ws[MSUM_OFF];
}

__global__ void k_h0(const float* __restrict__ W_init, const float* __restrict__ b_init, float* ws) {
  __shared__ float a_s[C_DIM];
  int tid = threadIdx.x;
  for (int i = tid; i < C_DIM; i += 256) a_s[i] = ws[AVG_OFF + i];
  __syncthreads();
  const float* wr = W_init + tid * C_DIM;
  float s = b_init[tid];
  for (int k = 0; k < C_DIM; k++) s += a_s[k] * wr[k];
  ws[H0_OFF + tid] = tanhf(s);
}

__global__ __launch_bounds__(512) void k_km(const float* __restrict__ convk,
                                            const float* __restrict__ Wcov, float* ws) {
  __shared__ float kt[256];
  int t = blockIdx.x, a = threadIdx.x;
  if (a < 256) kt[a] = convk[a * 121 + t];
  __syncthreads();
  const float* wr = Wcov + a * 256;
  float s = 0.f;
  for (int c = 0; c < 256; c++) s += kt[c] * wr[c];
  ws[KMT_OFF + a * 121 + t] = s;
}

__global__ void k_ct(const float* __restrict__ cnn, const float* __restrict__ Wproj,
                     const float* __restrict__ bproj, float* ws) {
  __shared__ float As[8][128];
  __shared__ float Bs[8][64];
  int hw0 = blockIdx.x * 128;
  int a0 = blockIdx.y * 64;
  int tid = threadIdx.x;
  int tx = tid & 15, ty = tid >> 4;
  float acc[8][4];
#pragma unroll
  for (int i = 0; i < 8; i++)
#pragma unroll
    for (int j = 0; j < 4; j++) acc[i][j] = 0.f;
  for (int c0 = 0; c0 < C_DIM; c0 += 8) {
    {
      int kk = tid >> 5;
      int m4 = (tid & 31) * 4;
      int c = c0 + kk;
      float4 v = make_float4(0.f, 0.f, 0.f, 0.f);
      if (c < C_DIM) v = *(const float4*)(cnn + c * HW + hw0 + m4);
      *(float4*)&As[kk][m4] = v;
    }
    {
      int n = tid & 63;
      int kk0 = (tid >> 6) * 2;
      const float* wr = Wproj + (a0 + n) * C_DIM + c0;
      Bs[kk0][n]     = (c0 + kk0 < C_DIM) ? wr[kk0] : 0.f;
      Bs[kk0 + 1][n] = (c0 + kk0 + 1 < C_DIM) ? wr[kk0 + 1] : 0.f;
    }
    __syncthreads();
#pragma unroll
    for (int kk = 0; kk < 8; kk++) {
      float a8[8], b4[4];
#pragma unroll
      for (int i = 0; i < 8; i++) a8[i] = As[kk][ty * 8 + i];
#pragma unroll
      for (int j = 0; j < 4; j++) b4[j] = Bs[kk][tx * 4 + j];
#pragma unroll
      for (int i = 0; i < 8; i++)
#pragma unroll
        for (int j = 0; j < 4; j++) acc[i][j] += a8[i] * b4[j];
    }
    __syncthreads();
  }
#pragma unroll
  for (int i = 0; i < 8; i++) {
    int hw = hw0 + ty * 8 + i;
#pragma unroll
    for (int j = 0; j < 4; j++) {
      int a = a0 + tx * 4 + j;
      ws[CT_OFF + hw * A_DIM + a] = acc[i][j] + bproj[a];
    }
  }
}

__global__ void k_gi(const float* __restrict__ emb_table, const float* __restrict__ Wih_in,
                     const float* __restrict__ bih_in, float* ws) {
  __shared__ float e_s[256];
  int v = blockIdx.x, tid = threadIdx.x;
  e_s[tid] = emb_table[v * 256 + tid];
  __syncthreads();
#pragma unroll
  for (int r = 0; r < 3; r++) {
    int m = r * 256 + tid;
    const float* wr = Wih_in + m * 256;
    float s = bih_in[m];
    for (int k = 0; k < 256; k++) s += e_s[k] * wr[k];
    ws[GI_OFF + v * 768 + m] = s;
  }
}

__global__ void k_se(const float* __restrict__ emb_table, const float* __restrict__ We,
                     const float* __restrict__ be, float* ws) {
  __shared__ float e_s[256];
  int v = blockIdx.x, tid = threadIdx.x;  // 128
  e_s[tid] = emb_table[v * 256 + tid];
  e_s[tid + 128] = emb_table[v * 256 + tid + 128];
  __syncthreads();
  const float* wr = We + tid * 256;
  float s = be[tid];
  for (int k = 0; k < 256; k++) s += e_s[k] * wr[k];
  ws[SE_OFF + v * 128 + tid] = s;
}

__global__ void k_tr(const float* __restrict__ in, float* __restrict__ out, int M, int Kd) {
  int total = M * Kd;
  for (int i = blockIdx.x * blockDim.x + threadIdx.x; i < total; i += gridDim.x * blockDim.x) {
    int m = i / Kd, k = i - m * Kd;
    out[k * M + m] = in[i];
  }
}

// bootstrap 1: h1(0) slices -> H1V slot0 (word = 1)
__global__ __launch_bounds__(512) void k_pre0(const float* __restrict__ Whh_in,
                                              const float* __restrict__ bhh_in, float* ws) {
  __shared__ float h0s[256];
  __shared__ float ghn48[48];
  const int s = blockIdx.x, tid = threadIdx.x;
  const int j0 = s * 16;
  if (tid < 256) h0s[tid] = ws[H0_OFF + tid];
  __syncthreads();
  {
    int r = tid >> 3, l = tid & 7;
    if (r < 48) {
      int mg = (r >> 4) * 256 + j0 + (r & 15);
      const float* wr = Whh_in + mg * 256 + l * 32;
      float sm = 0.f;
#pragma unroll
      for (int k = 0; k < 32; k++) sm += h0s[l * 32 + k] * wr[k];
#pragma unroll
      for (int off = 4; off; off >>= 1) sm += __shfl_xor(sm, off, 8);
      if (l == 0) ghn48[r] = sm + bhh_in[mg];
    }
  }
  __syncthreads();
  if (tid < 16) {
    int j = j0 + tid;
    const float* gi = ws + GI_OFF + 1 * 768;
    float r = sigmoidf_(gi[j] + ghn48[tid]);
    float z = sigmoidf_(gi[256 + j] + ghn48[16 + tid]);
    float n = tanhf(gi[512 + j] + r * ghn48[32 + tid]);
    gst(ws + H1V_OFF + j, (1.f - z) * n + z * h0s[j]);  // slot 0
  }
}

// bootstrap 2: q(0) and gho(0) slices from H1V slot0
__global__ __launch_bounds__(512) void k_pre1(const float* __restrict__ Wq,
                                              const float* __restrict__ Whh_out,
                                              const float* __restrict__ bhh_out, float* ws) {
  __shared__ float h1s[256];
  const int s = blockIdx.x, tid = threadIdx.x;
  if (tid < 256) h1s[tid] = gld(ws + H1V_OFF + tid);
  __syncthreads();
  {
    int ap = tid >> 4, l = tid & 15;
    int a = s * 32 + ap;
    const float* wr = Wq + a * 256 + l * 16;
    float sm = 0.f;
#pragma unroll
    for (int k = 0; k < 16; k++) sm += h1s[l * 16 + k] * wr[k];
#pragma unroll
    for (int off = 8; off; off >>= 1) sm += __shfl_xor(sm, off, 16);
    if (l == 0) gst(ws + QV_OFF + a, sm);
  }
  {
    int r = tid >> 3, l = tid & 7;
    if (r < 48) {
      int m = s * 48 + r;
      const float* wr = Whh_out + m * 256 + l * 32;
      float sm = 0.f;
#pragma unroll
      for (int k = 0; k < 32; k++) sm += h1s[l * 32 + k] * wr[k];
#pragma unroll
      for (int off = 4; off; off >>= 1) sm += __shfl_xor(sm, off, 8);
      if (l == 0) gst(ws + GHOV_OFF + m, sm + bhh_out[m]);  // slot 0
    }
  }
}

__global__ void k_go(float* ws) {
  int tid = threadIdx.x;
  if (tid < 128) ((int*)(ws + TQR_OFF))[tid * 16] = 1;  // q(0) ready
}

// ---------------- persistent kernel ----------------
// step t: TQR>=t+1 -> E tanh -> EF -> mono AFR -> ctx (ctxv 32B) -> CF -> mono CR ->
//   {GIO x16 / PSC x4: LDS-resident weight dots -> GIOV/PSCV -> GF/PSCF}
//   -> {mono: h,state,prob,argmax | tail: h, ghn->TF} -> mono h1 -> H1F
//   -> tail: gho(t+1), q(t+1) -> TQR=t+2.   E conv gated on CR(t).

__global__ __launch_bounds__(512) void k_steps(
    const float* __restrict__ cnn, const float* __restrict__ Whh_in,
    const float* __restrict__ Whh_out, const float* __restrict__ Wq,
    const float* __restrict__ Wih_out, const float* __restrict__ Wc_,
    const float* __restrict__ bq, const float* __restrict__ wa, const float* __restrict__ ba,
    const float* __restrict__ bih_out, const float* __restrict__ bhh_out,
    const float* __restrict__ bhh_in,
    const float* __restrict__ bs_, const float* __restrict__ bc_, const float* __restrict__ bv_,
    float* ws, float* __restrict__ out) {
  __shared__ __align__(16) float S[40016];

  const int bid = blockIdx.x, tid = threadIdx.x;
  int* flags = (int*)(ws + FLAGS_OFF);
  int* afr   = (int*)(ws + AFR_OFF);
  int* cr    = (int*)(ws + CR_OFF);
  int* h1f   = (int*)(ws + H1F_OFF);
  int* tqr   = (int*)(ws + TQR_OFF);

  if (bid < NERG) {
    // ================= ENERGY =================
    const int h_row = bid >> 2, aq = bid & 3, a0 = aq * 128;
    const int al = tid & 127, hslot = tid >> 7;
    float* km    = S;          // [128][132]
    float* ct    = S + 16896;  // [128][128]
    float* patch = S + 33280;  // [11][144]
    float* maskv = S + 34864;
    float* redE  = S + 34992;
    for (int i = tid; i < 128 * 132; i += 512) {
      int a = i / 132, j = i - a * 132;
      int dy = j / 12, dx = j - dy * 12;
      km[i] = (dx < 11) ? ws[KMT_OFF + (a0 + a) * 121 + dy * 11 + dx] : 0.f;
    }
    for (int i = tid; i < 128 * 128; i += 512) {
      int w = i >> 7, aa = i & 127;
      ct[i] = ws[CT_OFF + (h_row * 128 + w) * 512 + a0 + aa];
    }
    if (tid < 128) maskv[tid] = ws[MASK_OFF + h_row * 128 + tid];
    const float bq_a = bq[a0 + al], wa_a = wa[a0 + al], ba0 = ba[0];
    __syncthreads();

#pragma unroll 1
    for (int t = 0; t < T_STEPS; t++) {
      if (tid == 0) pollf(&cr[(bid & 7) * 16], t);  // apad(t) final
      __syncthreads();
      for (int i = tid; i < 11 * 138; i += 512) {
        int r = i / 138, c = i - r * 138;
        patch[r * 144 + c] = gld(ws + APAD_OFF + (h_row + r) * PADC + c);
      }
      __syncthreads();
      float acc[2][16];
#pragma unroll
      for (int p = 0; p < 2; p++)
#pragma unroll
        for (int i = 0; i < 16; i++) acc[p][i] = 0.f;
      const int wbase0 = hslot * 32;
#pragma unroll 1
      for (int dy = 0; dy < 11; dy++) {
        float kv[12];
        {
          const float* kb = &km[al * 132 + dy * 12];
          *(float4*)&kv[0] = *(const float4*)&kb[0];
          *(float4*)&kv[4] = *(const float4*)&kb[4];
          *(float4*)&kv[8] = *(const float4*)&kb[8];
        }
#pragma unroll
        for (int p = 0; p < 2; p++) {
          float row[28];
          const float* pr = &patch[dy * 144 + wbase0 + p * 16];
#pragma unroll
          for (int i = 0; i < 7; i++) *(float4*)&row[i * 4] = *(const float4*)&pr[i * 4];
#pragma unroll
          for (int dx = 0; dx < 11; dx++)
#pragma unroll
            for (int wi = 0; wi < 16; wi++) acc[p][wi] += kv[dx] * row[wi + dx];
        }
      }
      // q gate
      if (tid < 16) pollf(&tqr[(tid * 8 + (bid & 7)) * 16], t + 1);
      __syncthreads();
      float qa = bq_a + gld(ws + QV_OFF + a0 + al);
#pragma unroll 1
      for (int p = 0; p < 2; p++) {
        const int wbase = wbase0 + p * 16;
#pragma unroll
        for (int wi = 0; wi < 16; wi++) {
          float x = acc[p][wi] + qa + ct[(wbase + wi) * 128 + al];
          float v = ftanh(x) * wa_a;
#pragma unroll
          for (int off = 32; off; off >>= 1) v += __shfl_xor(v, off, 64);
          if ((tid & 63) == 0) redE[(tid >> 6) * 16 + wi] = v;
        }
        __syncthreads();
        if (tid < 64) {
          int hs2 = tid >> 4, wi = tid & 15;
          int w = hs2 * 32 + p * 16 + wi;
          float e = redE[(hs2 * 2) * 16 + wi] + redE[(hs2 * 2 + 1) * 16 + wi];
          float val = (maskv[w] > 0.f) ? (e + (aq == 0 ? ba0 : 0.f)) : -2.5e8f;
          gst(ws + PART_OFF + aq * 4096 + h_row * 128 + w, val);
        }
        __syncthreads();
      }
      if (tid == 0) rel_store(&flags[bid * 16], t + 1);
    }

  } else if (bid < CTX0 + NCTXB) {
    // ================= CTX (emits ctxv[8] + apad only) =================
    const int cb = bid - CTX0, c0 = cb * 8;
    float* cnnS = S;           // 32768
    float* redC = S + 32768;   // 64
    float* ctxv = S + 32832;   // 8
    float* invp = S + 32840;
    for (int i = tid; i < 8 * 4096; i += 512) {
      int c = c0 + (i >> 12);
      cnnS[i] = (c < C_DIM) ? cnn[c * 4096 + (i & 4095)] : 0.f;
    }
    __syncthreads();

#pragma unroll 1
    for (int t = 0; t < T_STEPS; t++) {
      if (tid == 0) pollf(&afr[(bid & 7) * 16], t + 1);
      __syncthreads();
      float ev[8];
      float ssum = 0.f;
#pragma unroll
      for (int j = 0; j < 8; j++) {
        int hw = j * 512 + tid;
        float e = gld(ws + PART_OFF + hw) + gld(ws + PART_OFF + 4096 + hw) +
                  gld(ws + PART_OFF + 8192 + hw) + gld(ws + PART_OFF + 12288 + hw);
        ev[j] = __expf(e);
        ssum += ev[j];
      }
#pragma unroll
      for (int off = 32; off; off >>= 1) ssum += __shfl_xor(ssum, off, 64);
      if ((tid & 63) == 0) redC[tid >> 6] = ssum;
      __syncthreads();
      if (tid == 0) {
        float s2 = 0.f;
#pragma unroll
        for (int i = 0; i < 8; i++) s2 += redC[i];
        invp[0] = 1.f / s2;
      }
      __syncthreads();
      float inv = invp[0];
      if (cb < 8) {
        int hw = cb * 512 + tid;
        int hh = hw >> 7, ww = hw & 127;
        float* ap = ws + APAD_OFF + (hh + 5) * PADC + ww + 5;
        gst(ap, gld(ap) + ev[cb] * inv);
      }
#pragma unroll
      for (int cc = 0; cc < 8; cc++) {
        float p = 0.f;
#pragma unroll
        for (int j = 0; j < 8; j++) p += ev[j] * cnnS[cc * 4096 + j * 512 + tid];
#pragma unroll
        for (int off = 32; off; off >>= 1) p += __shfl_xor(p, off, 64);
        if ((tid & 63) == 0) redC[(tid >> 6) * 8 + cc] = p;
      }
      __syncthreads();
      if (tid < 8) {
        float cv = 0.f;
#pragma unroll
        for (int w2 = 0; w2 < 8; w2++) cv += redC[w2 * 8 + tid];
        gst(ws + CTXV_OFF + c0 + tid, cv * inv);
      }
      __syncthreads();
      if (tid == 0) rel_store(&flags[(CTX0 + cb) * 16], t + 1);
    }

  } else if (bid == MONO) {
    // ================= MONO: relays + h, state, prob, argmax, h1 =================
    float* wst  = S;             // [256][128]
    float* mh   = S + 32768;     // 256
    float* mst  = S + 33024;     // 128
    float* wval = S + 33152;     // 8
    int*   widx = (int*)(S + 33160);  // 8
    int*   mwp  = (int*)(S + 33168);
    int*   mwn  = (int*)(S + 33169);
    for (int i = tid; i < 256 * 128; i += 512) wst[i] = ws[WST_OFF + i];
    if (tid == 0) mwp[0] = 1;
    __syncthreads();

#pragma unroll 1
    for (int t = 0; t < T_STEPS; t++) {
      const int par = t & 1;
      // A: EF collect -> AFR
      if (tid < 128) pollf(&flags[tid * 16], t + 1);
      __syncthreads();
      if (tid < 8) rel_store(&afr[tid * 16], t + 1);
      // prefetch gho/h1v (safe: EF => TQR(t+1) => tails finished slot par)
      float o0 = 0.f, o1 = 0.f, o2 = 0.f, h1v = 0.f;
      if (tid < 256) {
        const float* gh = ws + GHOV_OFF + par * 768;
        o0 = gld(gh + tid);
        o1 = gld(gh + 256 + tid);
        o2 = gld(gh + 512 + tid);
        h1v = gld(ws + H1V_OFF + par * 256 + tid);
      }
      // B: CF collect -> CR
      if (tid < NCTXB) pollf(&flags[(CTX0 + tid) * 16], t + 1);
      __syncthreads();
      if (tid < 8) rel_store(&cr[tid * 16], t + 1);
      // C: GF + PSCF poll
      if (tid < 16) pollf(&flags[(230 + tid) * 16], t + 1);
      else if (tid < 20) pollf(&flags[(246 + tid - 16) * 16], t + 1);
      __syncthreads();
      // h(t)
      if (tid < 256) {
        float g0 = gld(ws + GIOV_OFF + tid);
        float g1 = gld(ws + GIOV_OFF + 256 + tid);
        float g2 = gld(ws + GIOV_OFF + 512 + tid);
        float r = sigmoidf_(g0 + o0);
        float z = sigmoidf_(g1 + o1);
        float n = tanhf(g2 + r * o2);
        mh[tid] = (1.f - z) * n + z * h1v;
      }
      __syncthreads();
      // state
      if (tid < 128) {
        float s = bs_[tid] + bc_[tid] + ws[SE_OFF + mwp[0] * 128 + tid] +
                  gld(ws + PSCV_OFF + tid);
        const float* wt = wst + tid;
#pragma unroll 8
        for (int k = 0; k < 256; k++) s += mh[k] * wt[k * 128];
        mst[tid] = s;
      }
      __syncthreads();
      // prob + wave-shuffle argmax
      {
        float best = -3.4e38f;
        int bi = tid;
        if (tid < V_DIM) {
          float p2 = bv_[tid];
          const float* wt = ws + WVT_OFF + tid;
#pragma unroll 8
          for (int k = 0; k < 128; k++) p2 += mst[k] * wt[k * V_DIM];
          out[t * V_DIM + tid] = p2;
          best = p2;
        }
#pragma unroll
        for (int off = 32; off; off >>= 1) {
          float ov = __shfl_xor(best, off, 64);
          int oi = __shfl_xor(bi, off, 64);
          if (ov > best || (ov == best && oi < bi)) { best = ov; bi = oi; }
        }
        if ((tid & 63) == 0) { wval[tid >> 6] = best; widx[tid >> 6] = bi; }
        __syncthreads();
        if (tid == 0) {
          float b0 = wval[0];
          int i0 = widx[0];
          for (int w2 = 1; w2 < 8; w2++) {
            if (wval[w2] > b0 || (wval[w2] == b0 && widx[w2] < i0)) {
              b0 = wval[w2];
              i0 = widx[w2];
            }
          }
          mwn[0] = i0;
        }
        __syncthreads();
      }
      // ghn ready (TF)
      if (tid < 16) pollf(&flags[(214 + tid) * 16], t + 1);
      __syncthreads();
      // h1(t+1)
      if (tid < 256) {
        const float* gi = ws + GI_OFF + mwn[0] * 768;
        float n0 = gld(ws + GHNV_OFF + tid);
        float n1 = gld(ws + GHNV_OFF + 256 + tid);
        float n2 = gld(ws + GHNV_OFF + 512 + tid);
        float r = sigmoidf_(gi[tid] + n0);
        float z = sigmoidf_(gi[256 + tid] + n1);
        float n = tanhf(gi[512 + tid] + r * n2);
        gst(ws + H1V_OFF + ((t + 1) & 1) * 256 + tid, (1.f - z) * n + z * mh[tid]);
      }
      __syncthreads();
      if (tid < 8) rel_store(&h1f[tid * 16], t + 1);
      if (tid == 0) mwp[0] = mwn[0];
      __syncthreads();
    }

  } else if (bid < GIO0) {
    // ================= TAIL s (ghn, gho, q; LDS weights, conflict-free) =================
    const int s = bid - TAIL0;
    float* whinS = S;            // [48][264]
    float* whoS  = S + 12672;    // [48][264]
    float* wqS   = S + 25344;    // [32][264]
    float* hS    = S + 33792;    // 256
    float* h1S   = S + 34048;    // 256
    for (int i = tid; i < 48 * 256; i += 512) whinS[(i >> 8) * 264 + (i & 255)] = Whh_in[s * 12288 + i];
    for (int i = tid; i < 48 * 256; i += 512) whoS[(i >> 8) * 264 + (i & 255)] = Whh_out[s * 12288 + i];
    for (int i = tid; i < 32 * 256; i += 512) wqS[(i >> 8) * 264 + (i & 255)] = Wq[s * 8192 + i];
    __syncthreads();

#pragma unroll 1
    for (int t = 0; t < T_STEPS; t++) {
      const int par = t & 1;
      if (tid < 16) pollf(&flags[(230 + tid) * 16], t + 1);  // GF
      __syncthreads();
      if (tid < 256) {
        float g0 = gld(ws + GIOV_OFF + tid);
        float g1 = gld(ws + GIOV_OFF + 256 + tid);
        float g2 = gld(ws + GIOV_OFF + 512 + tid);
        const float* gh = ws + GHOV_OFF + par * 768;
        float o0 = gld(gh + tid), o1 = gld(gh + 256 + tid), o2 = gld(gh + 512 + tid);
        float h1v = gld(ws + H1V_OFF + par * 256 + tid);
        float r = sigmoidf_(g0 + o0);
        float z = sigmoidf_(g1 + o1);
        float n = tanhf(g2 + r * o2);
        hS[tid] = (1.f - z) * n + z * h1v;
      }
      __syncthreads();
      // ghn slice
      {
        int r = tid >> 3, l = tid & 7;
        if (r < 48) {
          int m = s * 48 + r;
          float sm = 0.f;
#pragma unroll
          for (int jj = 0; jj < 8; jj++) {
            float4 w4 = *(const float4*)&whinS[r * 264 + jj * 32 + l * 4];
            float4 h4 = *(const float4*)&hS[jj * 32 + l * 4];
            sm += w4.x * h4.x + w4.y * h4.y + w4.z * h4.z + w4.w * h4.w;
          }
#pragma unroll
          for (int off = 4; off; off >>= 1) sm += __shfl_xor(sm, off, 8);
          if (l == 0) gst(ws + GHNV_OFF + m, sm + bhh_in[m]);
        }
      }
      __syncthreads();
      if (tid == 0) rel_store(&flags[(214 + s) * 16], t + 1);  // TF
      if (tid == 0) pollf(&h1f[(s & 7) * 16], t + 1);
      __syncthreads();
      if (tid < 256) h1S[tid] = gld(ws + H1V_OFF + ((t + 1) & 1) * 256 + tid);
      __syncthreads();
      // gho(t+1) slice
      {
        int r = tid >> 3, l = tid & 7;
        if (r < 48) {
          int m = s * 48 + r;
          float sm = 0.f;
#pragma unroll
          for (int jj = 0; jj < 8; jj++) {
            float4 w4 = *(const float4*)&whoS[r * 264 + jj * 32 + l * 4];
            float4 h4 = *(const float4*)&h1S[jj * 32 + l * 4];
            sm += w4.x * h4.x + w4.y * h4.y + w4.z * h4.z + w4.w * h4.w;
          }
#pragma unroll
          for (int off = 4; off; off >>= 1) sm += __shfl_xor(sm, off, 8);
          if (l == 0) gst(ws + GHOV_OFF + ((t + 1) & 1) * 768 + m, sm + bhh_out[m]);
        }
      }
      // q(t+1) slice
      {
        int ap = tid >> 4, l = tid & 15;
        int a = s * 32 + ap;
        float sm = 0.f;
#pragma unroll
        for (int jj = 0; jj < 4; jj++) {
          float4 w4 = *(const float4*)&wqS[ap * 264 + jj * 64 + l * 4];
          float4 h4 = *(const float4*)&h1S[jj * 64 + l * 4];
          sm += w4.x * h4.x + w4.y * h4.y + w4.z * h4.z + w4.w * h4.w;
        }
#pragma unroll
        for (int off = 8; off; off >>= 1) sm += __shfl_xor(sm, off, 16);
        if (l == 0) gst(ws + QV_OFF + a, sm);
      }
      __syncthreads();
      if (tid < 8) rel_store(&tqr[(s * 8 + tid) * 16], t + 2);
    }

  } else if (bid < PSC0) {
    // ================= GIO g: final gio rows from ctxv (LDS-resident weights) =================
    const int g = bid - GIO0;
    float* wS  = S;           // [48][690]
    float* cvS = S + 33120;   // 704
    for (int i = tid; i < 48 * 684; i += 512) {
      int r = i / 684, c = i - r * 684;
      wS[r * 690 + c] = Wih_out[(g * 48 + r) * 684 + c];
    }
    __syncthreads();
#pragma unroll 1
    for (int t = 0; t < T_STEPS; t++) {
      if (tid == 0) pollf(&cr[(bid & 7) * 16], t + 1);
      __syncthreads();
      for (int i = tid; i < 684; i += 512) cvS[i] = gld(ws + CTXV_OFF + i);
      __syncthreads();
      {
        int r = tid >> 3, l = tid & 7;
        if (r < 48) {
          float sm = 0.f;
          for (int k = l; k < 684; k += 8) sm += wS[r * 690 + k] * cvS[k];
#pragma unroll
          for (int off = 4; off; off >>= 1) sm += __shfl_xor(sm, off, 8);
          if (l == 0) {
            int m = g * 48 + r;
            gst(ws + GIOV_OFF + m, sm + bih_out[m]);
          }
        }
      }
      __syncthreads();
      if (tid == 0) rel_store(&flags[(230 + g) * 16], t + 1);  // GF
    }

  } else {
    // ================= PSC p: final psc rows from ctxv =================
    const int p = bid - PSC0;
    float* wS  = S;           // [32][690]
    float* cvS = S + 22080;   // 704
    for (int i = tid; i < 32 * 684; i += 512) {
      int r = i / 684, c = i - r * 684;
      wS[r * 690 + c] = Wc_[(p * 32 + r) * 684 + c];
    }
    __syncthreads();
#pragma unroll 1
    for (int t = 0; t < T_STEPS; t++) {
      if (tid == 0) pollf(&cr[(bid & 7) * 16], t + 1);
      __syncthreads();
      for (int i = tid; i < 684; i += 512) cvS[i] = gld(ws + CTXV_OFF + i);
      __syncthreads();
      {
        int r = tid >> 4, l = tid & 15;
        if (r < 32) {
          float sm = 0.f;
          for (int k = l; k < 684; k += 16) sm += wS[r * 690 + k] * cvS[k];
#pragma unroll
          for (int off = 8; off; off >>= 1) sm += __shfl_xor(sm, off, 16);
          if (l == 0) gst(ws + PSCV_OFF + p * 32 + r, sm);
        }
      }
      __syncthreads();
      if (tid == 0) rel_store(&flags[(246 + p) * 16], t + 1);  // PSCF
    }
  }
}

// ---------------- host ----------------

extern "C" void kernel_launch(void* const* d_in, const int* in_sizes, int n_in,
                              void* d_out, int out_size, void* d_ws, size_t ws_size,
                              hipStream_t stream) {
  (void)in_sizes; (void)n_in; (void)out_size; (void)ws_size;
  const float* cnn      = (const float*)d_in[0];
  const float* imask    = (const float*)d_in[1];
  const float* emb_tab  = (const float*)d_in[2];
  const float* W_init   = (const float*)d_in[3];
  const float* b_init   = (const float*)d_in[4];
  const float* Wih_in   = (const float*)d_in[5];
  const float* Whh_in   = (const float*)d_in[6];
  const float* bih_in   = (const float*)d_in[7];
  const float* bhh_in   = (const float*)d_in[8];
  const float* Wih_out  = (const float*)d_in[9];
  const float* Whh_out  = (const float*)d_in[10];
  const float* bih_out  = (const float*)d_in[11];
  const float* bhh_out  = (const float*)d_in[12];
  const float* Wq       = (const float*)d_in[13];
  const float* bq       = (const float*)d_in[14];
  const float* Wproj    = (const float*)d_in[15];
  const float* bproj    = (const float*)d_in[16];
  const float* convk    = (const float*)d_in[17];
  const float* Wcov     = (const float*)d_in[18];
  const float* Ws_      = (const float*)d_in[21];
  const float* bs_      = (const float*)d_in[22];
  const float* We_      = (const float*)d_in[23];
  const float* be_      = (const float*)d_in[24];
  const float* Wc_      = (const float*)d_in[25];
  const float* bc_      = (const float*)d_in[26];
  const float* Wv_      = (const float*)d_in[27];
  const float* bv_      = (const float*)d_in[28];
  const float* wa       = (const float*)d_in[19];
  const float* ba       = (const float*)d_in[20];
  float* ws  = (float*)d_ws;
  float* out = (float*)d_out;

  k_init<<<1, 256, 0, stream>>>(imask, ws);
  k_avg<<<C_DIM, 256, 0, stream>>>(cnn, ws);
  k_h0<<<1, 256, 0, stream>>>(W_init, b_init, ws);
  k_km<<<121, 512, 0, stream>>>(convk, Wcov, ws);
  k_ct<<<dim3(HW / 128, A_DIM / 64), 256, 0, stream>>>(cnn, Wproj, bproj, ws);
  k_gi<<<V_DIM, 256, 0, stream>>>(emb_tab, Wih_in, bih_in, ws);
  k_se<<<V_DIM, 128, 0, stream>>>(emb_tab, We_, be_, ws);
  k_tr<<<512, 256, 0, stream>>>(Ws_, ws + WST_OFF, 128, 256);
  k_tr<<<512, 256, 0, stream>>>(Wv_, ws + WVT_OFF, 415, 128);
  k_pre0<<<16, 512, 0, stream>>>(Whh_in, bhh_in, ws);
  k_pre1<<<16, 512, 0, stream>>>(Wq, Whh_out, bhh_out, ws);
  k_go<<<1, 256, 0, stream>>>(ws);

  k_steps<<<NGRID, 512, 0, stream>>>(cnn, Whh_in, Whh_out, Wq, Wih_out, Wc_,
                                     bq, wa, ba, bih_out, bhh_out, bhh_in,
                                     bs_, bc_, bv_, ws, out);
}

// Round 17
// 2733.633 us; speedup vs baseline: 1.4907x; 1.0061x over previous
//
#include <hip/hip_runtime.h>
#include <math.h>

#define HF 32
#define WF 128
#define HW 4096
#define C_DIM 684
#define H_DIM 256
#define A_DIM 512
#define V_DIM 415
#define PADR 42
#define PADC 144
#define T_STEPS 64

#define NERG 128
#define CTX0 128
#define NCTXB 86
#define MONO 214
#define TAIL0 215   // 16 tail 215..230
#define GIO0 231    // 16 gio 231..246
#define PSC0 247    // 4 psc 247..250
#define NGRID 251

// ---------------- workspace layout (float offsets) ----------------
constexpr int CT_OFF      = 0;                        // [4096][512]
constexpr int KMT_OFF     = CT_OFF + HW * A_DIM;      // [512][121]
constexpr int APAD_OFF    = KMT_OFF + 61952;          // [42][144] mutable
constexpr int MASK_OFF    = APAD_OFF + 6048;
constexpr int PART_OFF    = MASK_OFF + 4096;          // [4][4096] mutable
constexpr int AVG_OFF     = PART_OFF + 16384;         // 704
constexpr int H0_OFF      = AVG_OFF + 704;            // 256
constexpr int QV_OFF      = H0_OFF + 256;             // [512] mutable
constexpr int H1V_OFF     = QV_OFF + 512;             // [2][256] mutable
constexpr int GHOV_OFF    = H1V_OFF + 512;            // [2][768] mutable
constexpr int GHNV_OFF    = GHOV_OFF + 1536;          // [768] mutable
constexpr int GIOV_OFF    = GHNV_OFF + 768;           // [768] mutable (bias included)
constexpr int PSCV_OFF    = GIOV_OFF + 768;           // [128] mutable
constexpr int CTXV_OFF    = PSCV_OFF + 128;           // [704] mutable
constexpr int MSUM_OFF    = CTXV_OFF + 704;           // 16
// ---- contiguous SYNC region (x16-int lines) ----
constexpr int EFR_OFF     = MSUM_OFF + 16;            // [128 e][8 r] = 1024 lines
constexpr int CFR_OFF     = EFR_OFF + 1024 * 16;      // [86 c][8 r] = 688 lines
constexpr int TF_OFF      = CFR_OFF + 688 * 16;       // 16 lines
constexpr int GF_OFF      = TF_OFF + 16 * 16;         // 16 lines
constexpr int PSCF_OFF    = GF_OFF + 16 * 16;         // 4 lines
constexpr int CR_OFF      = PSCF_OFF + 4 * 16;        // 8 lines (E conv gate)
constexpr int H1F_OFF     = CR_OFF + 8 * 16;          // 8 lines
constexpr int TQR_OFF     = H1F_OFF + 8 * 16;         // [16 s][8 r] = 128 lines
constexpr int SYNC_INTS   = (1024 + 688 + 16 + 16 + 4 + 8 + 8 + 128) * 16;  // 30272
constexpr int SYNC_END    = EFR_OFF + SYNC_INTS;
// ---- tables ----
constexpr int GI_OFF      = SYNC_END;                 // [415][768]
constexpr int SE_OFF      = GI_OFF + V_DIM * 768;     // [415][128]
constexpr int WST_OFF     = SE_OFF + V_DIM * 128;     // [256][128]
constexpr int WVT_OFF     = WST_OFF + 256 * 128;      // [128][415]
constexpr int WS_END      = WVT_OFF + 128 * V_DIM;

__device__ __forceinline__ float sigmoidf_(float x) { return 1.f / (1.f + expf(-x)); }
__device__ __forceinline__ float ftanh(float x) {
  float e = __expf(2.f * x);
  return 1.f - 2.f / (e + 1.f);
}

__device__ __forceinline__ float gld(const float* p) {
  int v = __hip_atomic_load((const int*)p, __ATOMIC_RELAXED, __HIP_MEMORY_SCOPE_AGENT);
  return __int_as_float(v);
}
__device__ __forceinline__ void gst(float* p, float x) {
  __hip_atomic_store((int*)p, __float_as_int(x), __ATOMIC_RELAXED, __HIP_MEMORY_SCOPE_AGENT);
}
__device__ __forceinline__ void pollf(int* p, int ph) {
  int it = 0;
  while (__hip_atomic_load(p, __ATOMIC_RELAXED, __HIP_MEMORY_SCOPE_AGENT) < ph) {
    if (it < 4) __builtin_amdgcn_s_sleep(1);
    else if (it < 16) __builtin_amdgcn_s_sleep(4);
    else __builtin_amdgcn_s_sleep(8);
    ++it;
  }
  asm volatile("" ::: "memory");
}
__device__ __forceinline__ void rel_store(int* p, int v) {
  __hip_atomic_store(p, v, __ATOMIC_RELEASE, __HIP_MEMORY_SCOPE_AGENT);
}

// ---------------- precompute ----------------

__global__ void k_init(const float* __restrict__ imask, float* ws) {
  __shared__ float red[4];
  int tid = threadIdx.x;
  float s = 0.f;
  for (int i = tid; i < HW; i += 256) {
    int h = i >> 7, w = i & 127;
    float m = imask[h * 16 * 2048 + w * 16];
    ws[MASK_OFF + i] = m;
    s += m;
  }
  for (int i = tid; i < PADR * PADC; i += 256) ws[APAD_OFF + i] = 0.f;
  int* sync = (int*)(ws + EFR_OFF);
  for (int i = tid; i < SYNC_INTS; i += 256) sync[i] = 0;
#pragma unroll
  for (int off = 32; off; off >>= 1) s += __shfl_xor(s, off, 64);
  if ((tid & 63) == 0) red[tid >> 6] = s;
  __syncthreads();
  if (tid == 0) ws[MSUM_OFF] = red[0] + red[1] + red[2] + red[3];
}

__global__ void k_avg(const float* __restrict__ cnn, float* ws) {
  __shared__ float red[4];
  int c = blockIdx.x, tid = threadIdx.x;
  const float* row = cnn + c * HW;
  float s = 0.f;
  for (int i = tid; i < HW; i += 256) s += ws[MASK_OFF + i] * row[i];
#pragma unroll
  for (int off = 32; off; off >>= 1) s += __shfl_xor(s, off, 64);
  if ((tid & 63) == 0) red[tid >> 6] = s;
  __syncthreads();
  if (tid == 0) ws[AVG_OFF + c] = (red[0] + red[1] + red[2] + red[3]) / ws[MSUM_OFF];
}

__global__ void k_h0(const float* __restrict__ W_init, const float* __restrict__ b_init, float* ws) {
  __shared__ float a_s[C_DIM];
  int tid = threadIdx.x;
  for (int i = tid; i < C_DIM; i += 256) a_s[i] = ws[AVG_OFF + i];
  __syncthreads();
  const float* wr = W_init + tid * C_DIM;
  float s = b_init[tid];
  for (int k = 0; k < C_DIM; k++) s += a_s[k] * wr[k];
  ws[H0_OFF + tid] = tanhf(s);
}

__global__ __launch_bounds__(512) void k_km(const float* __restrict__ convk,
                                            const float* __restrict__ Wcov, float* ws) {
  __shared__ float kt[256];
  int t = blockIdx.x, a = threadIdx.x;
  if (a < 256) kt[a] = convk[a * 121 + t];
  __syncthreads();
  const float* wr = Wcov + a * 256;
  float s = 0.f;
  for (int c = 0; c < 256; c++) s += kt[c] * wr[c];
  ws[KMT_OFF + a * 121 + t] = s;
}

__global__ void k_ct(const float* __restrict__ cnn, const float* __restrict__ Wproj,
                     const float* __restrict__ bproj, float* ws) {
  __shared__ float As[8][128];
  __shared__ float Bs[8][64];
  int hw0 = blockIdx.x * 128;
  int a0 = blockIdx.y * 64;
  int tid = threadIdx.x;
  int tx = tid & 15, ty = tid >> 4;
  float acc[8][4];
#pragma unroll
  for (int i = 0; i < 8; i++)
#pragma unroll
    for (int j = 0; j < 4; j++) acc[i][j] = 0.f;
  for (int c0 = 0; c0 < C_DIM; c0 += 8) {
    {
      int kk = tid >> 5;
      int m4 = (tid & 31) * 4;
      int c = c0 + kk;
      float4 v = make_float4(0.f, 0.f, 0.f, 0.f);
      if (c < C_DIM) v = *(const float4*)(cnn + c * HW + hw0 + m4);
      *(float4*)&As[kk][m4] = v;
    }
    {
      int n = tid & 63;
      int kk0 = (tid >> 6) * 2;
      const float* wr = Wproj + (a0 + n) * C_DIM + c0;
      Bs[kk0][n]     = (c0 + kk0 < C_DIM) ? wr[kk0] : 0.f;
      Bs[kk0 + 1][n] = (c0 + kk0 + 1 < C_DIM) ? wr[kk0 + 1] : 0.f;
    }
    __syncthreads();
#pragma unroll
    for (int kk = 0; kk < 8; kk++) {
      float a8[8], b4[4];
#pragma unroll
      for (int i = 0; i < 8; i++) a8[i] = As[kk][ty * 8 + i];
#pragma unroll
      for (int j = 0; j < 4; j++) b4[j] = Bs[kk][tx * 4 + j];
#pragma unroll
      for (int i = 0; i < 8; i++)
#pragma unroll
        for (int j = 0; j < 4; j++) acc[i][j] += a8[i] * b4[j];
    }
    __syncthreads();
  }
#pragma unroll
  for (int i = 0; i < 8; i++) {
    int hw = hw0 + ty * 8 + i;
#pragma unroll
    for (int j = 0; j < 4; j++) {
      int a = a0 + tx * 4 + j;
      ws[CT_OFF + hw * A_DIM + a] = acc[i][j] + bproj[a];
    }
  }
}

__global__ void k_gi(const float* __restrict__ emb_table, const float* __restrict__ Wih_in,
                     const float* __restrict__ bih_in, float* ws) {
  __shared__ float e_s[256];
  int v = blockIdx.x, tid = threadIdx.x;
  e_s[tid] = emb_table[v * 256 + tid];
  __syncthreads();
#pragma unroll
  for (int r = 0; r < 3; r++) {
    int m = r * 256 + tid;
    const float* wr = Wih_in + m * 256;
    float s = bih_in[m];
    for (int k = 0; k < 256; k++) s += e_s[k] * wr[k];
    ws[GI_OFF + v * 768 + m] = s;
  }
}

__global__ void k_se(const float* __restrict__ emb_table, const float* __restrict__ We,
                     const float* __restrict__ be, float* ws) {
  __shared__ float e_s[256];
  int v = blockIdx.x, tid = threadIdx.x;  // 128
  e_s[tid] = emb_table[v * 256 + tid];
  e_s[tid + 128] = emb_table[v * 256 + tid + 128];
  __syncthreads();
  const float* wr = We + tid * 256;
  float s = be[tid];
  for (int k = 0; k < 256; k++) s += e_s[k] * wr[k];
  ws[SE_OFF + v * 128 + tid] = s;
}

__global__ void k_tr(const float* __restrict__ in, float* __restrict__ out, int M, int Kd) {
  int total = M * Kd;
  for (int i = blockIdx.x * blockDim.x + threadIdx.x; i < total; i += gridDim.x * blockDim.x) {
    int m = i / Kd, k = i - m * Kd;
    out[k * M + m] = in[i];
  }
}

// bootstrap 1: h1(0) slices -> H1V slot0 (word = 1)
__global__ __launch_bounds__(512) void k_pre0(const float* __restrict__ Whh_in,
                                              const float* __restrict__ bhh_in, float* ws) {
  __shared__ float h0s[256];
  __shared__ float ghn48[48];
  const int s = blockIdx.x, tid = threadIdx.x;
  const int j0 = s * 16;
  if (tid < 256) h0s[tid] = ws[H0_OFF + tid];
  __syncthreads();
  {
    int r = tid >> 3, l = tid & 7;
    if (r < 48) {
      int mg = (r >> 4) * 256 + j0 + (r & 15);
      const float* wr = Whh_in + mg * 256 + l * 32;
      float sm = 0.f;
#pragma unroll
      for (int k = 0; k < 32; k++) sm += h0s[l * 32 + k] * wr[k];
#pragma unroll
      for (int off = 4; off; off >>= 1) sm += __shfl_xor(sm, off, 8);
      if (l == 0) ghn48[r] = sm + bhh_in[mg];
    }
  }
  __syncthreads();
  if (tid < 16) {
    int j = j0 + tid;
    const float* gi = ws + GI_OFF + 1 * 768;
    float r = sigmoidf_(gi[j] + ghn48[tid]);
    float z = sigmoidf_(gi[256 + j] + ghn48[16 + tid]);
    float n = tanhf(gi[512 + j] + r * ghn48[32 + tid]);
    gst(ws + H1V_OFF + j, (1.f - z) * n + z * h0s[j]);  // slot 0
  }
}

// bootstrap 2: q(0) and gho(0) slices from H1V slot0
__global__ __launch_bounds__(512) void k_pre1(const float* __restrict__ Wq,
                                              const float* __restrict__ Whh_out,
                                              const float* __restrict__ bhh_out, float* ws) {
  __shared__ float h1s[256];
  const int s = blockIdx.x, tid = threadIdx.x;
  if (tid < 256) h1s[tid] = gld(ws + H1V_OFF + tid);
  __syncthreads();
  {
    int ap = tid >> 4, l = tid & 15;
    int a = s * 32 + ap;
    const float* wr = Wq + a * 256 + l * 16;
    float sm = 0.f;
#pragma unroll
    for (int k = 0; k < 16; k++) sm += h1s[l * 16 + k] * wr[k];
#pragma unroll
    for (int off = 8; off; off >>= 1) sm += __shfl_xor(sm, off, 16);
    if (l == 0) gst(ws + QV_OFF + a, sm);
  }
  {
    int r = tid >> 3, l = tid & 7;
    if (r < 48) {
      int m = s * 48 + r;
      const float* wr = Whh_out + m * 256 + l * 32;
      float sm = 0.f;
#pragma unroll
      for (int k = 0; k < 32; k++) sm += h1s[l * 32 + k] * wr[k];
#pragma unroll
      for (int off = 4; off; off >>= 1) sm += __shfl_xor(sm, off, 8);
      if (l == 0) gst(ws + GHOV_OFF + m, sm + bhh_out[m]);  // slot 0
    }
  }
}

__global__ void k_go(float* ws) {
  int tid = threadIdx.x;
  if (tid < 128) ((int*)(ws + TQR_OFF))[tid * 16] = 1;  // q(0) ready, all 16x8 replicas
}

// ---------------- persistent kernel ----------------
// step t: TQR>=t+1 -> E tanh -> EFR (8 reps) -> ctx (direct poll) -> CFR (8 reps)
//   -> {GIO/PSC direct poll -> GIOV/PSCV -> GF/PSCF ; mono: CFR collect -> CR (E conv gate)}
//   -> {mono: h,state,prob,argmax | tail: h, ghn->TF} -> mono h1 -> H1F
//   -> tail: gho(t+1), q(t+1) -> TQR=t+2.   E conv gated on CR(t).

__global__ __launch_bounds__(512) void k_steps(
    const float* __restrict__ cnn, const float* __restrict__ Whh_in,
    const float* __restrict__ Whh_out, const float* __restrict__ Wq,
    const float* __restrict__ Wih_out, const float* __restrict__ Wc_,
    const float* __restrict__ bq, const float* __restrict__ wa, const float* __restrict__ ba,
    const float* __restrict__ bih_out, const float* __restrict__ bhh_out,
    const float* __restrict__ bhh_in,
    const float* __restrict__ bs_, const float* __restrict__ bc_, const float* __restrict__ bv_,
    float* ws, float* __restrict__ out) {
  __shared__ __align__(16) float S[40016];

  const int bid = blockIdx.x, tid = threadIdx.x;
  int* efr  = (int*)(ws + EFR_OFF);
  int* cfr  = (int*)(ws + CFR_OFF);
  int* tf   = (int*)(ws + TF_OFF);
  int* gf   = (int*)(ws + GF_OFF);
  int* pscf = (int*)(ws + PSCF_OFF);
  int* cr   = (int*)(ws + CR_OFF);
  int* h1f  = (int*)(ws + H1F_OFF);
  int* tqr  = (int*)(ws + TQR_OFF);

  if (bid < NERG) {
    // ================= ENERGY =================
    const int h_row = bid >> 2, aq = bid & 3, a0 = aq * 128;
    const int al = tid & 127, hslot = tid >> 7;
    float* km    = S;          // [128][132]
    float* ct    = S + 16896;  // [128][128]
    float* patch = S + 33280;  // [11][144]
    float* maskv = S + 34864;
    float* redE  = S + 34992;
    for (int i = tid; i < 128 * 132; i += 512) {
      int a = i / 132, j = i - a * 132;
      int dy = j / 12, dx = j - dy * 12;
      km[i] = (dx < 11) ? ws[KMT_OFF + (a0 + a) * 121 + dy * 11 + dx] : 0.f;
    }
    for (int i = tid; i < 128 * 128; i += 512) {
      int w = i >> 7, aa = i & 127;
      ct[i] = ws[CT_OFF + (h_row * 128 + w) * 512 + a0 + aa];
    }
    if (tid < 128) maskv[tid] = ws[MASK_OFF + h_row * 128 + tid];
    const float bq_a = bq[a0 + al], wa_a = wa[a0 + al], ba0 = ba[0];
    __syncthreads();

#pragma unroll 1
    for (int t = 0; t < T_STEPS; t++) {
      if (tid == 0) pollf(&cr[(bid & 7) * 16], t);  // apad(t) final
      __syncthreads();
      for (int i = tid; i < 11 * 138; i += 512) {
        int r = i / 138, c = i - r * 138;
        patch[r * 144 + c] = gld(ws + APAD_OFF + (h_row + r) * PADC + c);
      }
      __syncthreads();
      float acc[2][16];
#pragma unroll
      for (int p = 0; p < 2; p++)
#pragma unroll
        for (int i = 0; i < 16; i++) acc[p][i] = 0.f;
      const int wbase0 = hslot * 32;
#pragma unroll 1
      for (int dy = 0; dy < 11; dy++) {
        float kv[12];
        {
          const float* kb = &km[al * 132 + dy * 12];
          *(float4*)&kv[0] = *(const float4*)&kb[0];
          *(float4*)&kv[4] = *(const float4*)&kb[4];
          *(float4*)&kv[8] = *(const float4*)&kb[8];
        }
#pragma unroll
        for (int p = 0; p < 2; p++) {
          float row[28];
          const float* pr = &patch[dy * 144 + wbase0 + p * 16];
#pragma unroll
          for (int i = 0; i < 7; i++) *(float4*)&row[i * 4] = *(const float4*)&pr[i * 4];
#pragma unroll
          for (int dx = 0; dx < 11; dx++)
#pragma unroll
            for (int wi = 0; wi < 16; wi++) acc[p][wi] += kv[dx] * row[wi + dx];
        }
      }
      // q gate
      if (tid < 16) pollf(&tqr[(tid * 8 + (bid & 7)) * 16], t + 1);
      __syncthreads();
      float qa = bq_a + gld(ws + QV_OFF + a0 + al);
#pragma unroll 1
      for (int p = 0; p < 2; p++) {
        const int wbase = wbase0 + p * 16;
#pragma unroll
        for (int wi = 0; wi < 16; wi++) {
          float x = acc[p][wi] + qa + ct[(wbase + wi) * 128 + al];
          float v = ftanh(x) * wa_a;
#pragma unroll
          for (int off = 32; off; off >>= 1) v += __shfl_xor(v, off, 64);
          if ((tid & 63) == 0) redE[(tid >> 6) * 16 + wi] = v;
        }
        __syncthreads();
        if (tid < 64) {
          int hs2 = tid >> 4, wi = tid & 15;
          int w = hs2 * 32 + p * 16 + wi;
          float e = redE[(hs2 * 2) * 16 + wi] + redE[(hs2 * 2 + 1) * 16 + wi];
          float val = (maskv[w] > 0.f) ? (e + (aq == 0 ? ba0 : 0.f)) : -2.5e8f;
          gst(ws + PART_OFF + aq * 4096 + h_row * 128 + w, val);
        }
        __syncthreads();
      }
      if (tid < 8) rel_store(&efr[(bid * 8 + tid) * 16], t + 1);
    }

  } else if (bid < CTX0 + NCTXB) {
    // ================= CTX (polls EFR direct; emits ctxv[8] + apad) =================
    const int cb = bid - CTX0, c0 = cb * 8;
    float* cnnS = S;           // 32768
    float* redC = S + 32768;   // 64
    float* ctxv = S + 32832;   // 8
    float* invp = S + 32840;
    for (int i = tid; i < 8 * 4096; i += 512) {
      int c = c0 + (i >> 12);
      cnnS[i] = (c < C_DIM) ? cnn[c * 4096 + (i & 4095)] : 0.f;
    }
    __syncthreads();

#pragma unroll 1
    for (int t = 0; t < T_STEPS; t++) {
      if (tid < 128) pollf(&efr[(tid * 8 + (cb & 7)) * 16], t + 1);
      __syncthreads();
      float ev[8];
      float ssum = 0.f;
#pragma unroll
      for (int j = 0; j < 8; j++) {
        int hw = j * 512 + tid;
        float e = gld(ws + PART_OFF + hw) + gld(ws + PART_OFF + 4096 + hw) +
                  gld(ws + PART_OFF + 8192 + hw) + gld(ws + PART_OFF + 12288 + hw);
        ev[j] = __expf(e);
        ssum += ev[j];
      }
#pragma unroll
      for (int off = 32; off; off >>= 1) ssum += __shfl_xor(ssum, off, 64);
      if ((tid & 63) == 0) redC[tid >> 6] = ssum;
      __syncthreads();
      if (tid == 0) {
        float s2 = 0.f;
#pragma unroll
        for (int i = 0; i < 8; i++) s2 += redC[i];
        invp[0] = 1.f / s2;
      }
      __syncthreads();
      float inv = invp[0];
      if (cb < 8) {
        int hw = cb * 512 + tid;
        int hh = hw >> 7, ww = hw & 127;
        float* ap = ws + APAD_OFF + (hh + 5) * PADC + ww + 5;
        gst(ap, gld(ap) + ev[cb] * inv);
      }
#pragma unroll
      for (int cc = 0; cc < 8; cc++) {
        float p = 0.f;
#pragma unroll
        for (int j = 0; j < 8; j++) p += ev[j] * cnnS[cc * 4096 + j * 512 + tid];
#pragma unroll
        for (int off = 32; off; off >>= 1) p += __shfl_xor(p, off, 64);
        if ((tid & 63) == 0) redC[(tid >> 6) * 8 + cc] = p;
      }
      __syncthreads();
      if (tid < 8) {
        float cv = 0.f;
#pragma unroll
        for (int w2 = 0; w2 < 8; w2++) cv += redC[w2 * 8 + tid];
        gst(ws + CTXV_OFF + c0 + tid, cv * inv);
      }
      __syncthreads();
      if (tid < 8) rel_store(&cfr[(cb * 8 + tid) * 16], t + 1);
    }

  } else if (bid == MONO) {
    // ================= MONO: CR relay + h, state, prob, argmax, h1 =================
    float* wst  = S;             // [256][128]
    float* mh   = S + 32768;     // 256
    float* mst  = S + 33024;     // 128
    float* wval = S + 33152;     // 8
    int*   widx = (int*)(S + 33160);  // 8
    int*   mwp  = (int*)(S + 33168);
    int*   mwn  = (int*)(S + 33169);
    for (int i = tid; i < 256 * 128; i += 512) wst[i] = ws[WST_OFF + i];
    if (tid == 0) mwp[0] = 1;
    __syncthreads();

#pragma unroll 1
    for (int t = 0; t < T_STEPS; t++) {
      const int par = t & 1;
      // CF collect (replica 7) -> CR (E conv gate)
      if (tid < NCTXB) pollf(&cfr[(tid * 8 + 7) * 16], t + 1);
      __syncthreads();
      if (tid < 8) rel_store(&cr[tid * 16], t + 1);
      // prefetch gho/h1v (safe: CF => EF => TQR(t+1) => tails done with slot par)
      float o0 = 0.f, o1 = 0.f, o2 = 0.f, h1v = 0.f;
      if (tid < 256) {
        const float* gh = ws + GHOV_OFF + par * 768;
        o0 = gld(gh + tid);
        o1 = gld(gh + 256 + tid);
        o2 = gld(gh + 512 + tid);
        h1v = gld(ws + H1V_OFF + par * 256 + tid);
      }
      // GF + PSCF poll
      if (tid < 16) pollf(&gf[tid * 16], t + 1);
      else if (tid < 20) pollf(&pscf[(tid - 16) * 16], t + 1);
      __syncthreads();
      // h(t)
      if (tid < 256) {
        float g0 = gld(ws + GIOV_OFF + tid);
        float g1 = gld(ws + GIOV_OFF + 256 + tid);
        float g2 = gld(ws + GIOV_OFF + 512 + tid);
        float r = sigmoidf_(g0 + o0);
        float z = sigmoidf_(g1 + o1);
        float n = tanhf(g2 + r * o2);
        mh[tid] = (1.f - z) * n + z * h1v;
      }
      __syncthreads();
      // state
      if (tid < 128) {
        float s = bs_[tid] + bc_[tid] + ws[SE_OFF + mwp[0] * 128 + tid] +
                  gld(ws + PSCV_OFF + tid);
        const float* wt = wst + tid;
#pragma unroll 8
        for (int k = 0; k < 256; k++) s += mh[k] * wt[k * 128];
        mst[tid] = s;
      }
      __syncthreads();
      // prob + wave-shuffle argmax
      {
        float best = -3.4e38f;
        int bi = tid;
        if (tid < V_DIM) {
          float p2 = bv_[tid];
          const float* wt = ws + WVT_OFF + tid;
#pragma unroll 8
          for (int k = 0; k < 128; k++) p2 += mst[k] * wt[k * V_DIM];
          out[t * V_DIM + tid] = p2;
          best = p2;
        }
#pragma unroll
        for (int off = 32; off; off >>= 1) {
          float ov = __shfl_xor(best, off, 64);
          int oi = __shfl_xor(bi, off, 64);
          if (ov > best || (ov == best && oi < bi)) { best = ov; bi = oi; }
        }
        if ((tid & 63) == 0) { wval[tid >> 6] = best; widx[tid >> 6] = bi; }
        __syncthreads();
        if (tid == 0) {
          float b0 = wval[0];
          int i0 = widx[0];
          for (int w2 = 1; w2 < 8; w2++) {
            if (wval[w2] > b0 || (wval[w2] == b0 && widx[w2] < i0)) {
              b0 = wval[w2];
              i0 = widx[w2];
            }
          }
          mwn[0] = i0;
        }
        __syncthreads();
      }
      // ghn ready (TF)
      if (tid < 16) pollf(&tf[tid * 16], t + 1);
      __syncthreads();
      // h1(t+1)
      if (tid < 256) {
        const float* gi = ws + GI_OFF + mwn[0] * 768;
        float n0 = gld(ws + GHNV_OFF + tid);
        float n1 = gld(ws + GHNV_OFF + 256 + tid);
        float n2 = gld(ws + GHNV_OFF + 512 + tid);
        float r = sigmoidf_(gi[tid] + n0);
        float z = sigmoidf_(gi[256 + tid] + n1);
        float n = tanhf(gi[512 + tid] + r * n2);
        gst(ws + H1V_OFF + ((t + 1) & 1) * 256 + tid, (1.f - z) * n + z * mh[tid]);
      }
      __syncthreads();
      if (tid < 8) rel_store(&h1f[tid * 16], t + 1);
      if (tid == 0) mwp[0] = mwn[0];
      __syncthreads();
    }

  } else if (bid < GIO0) {
    // ================= TAIL s (ghn, gho, q; LDS weights, conflict-free) =================
    const int s = bid - TAIL0;
    float* whinS = S;            // [48][264]
    float* whoS  = S + 12672;    // [48][264]
    float* wqS   = S + 25344;    // [32][264]
    float* hS    = S + 33792;    // 256
    float* h1S   = S + 34048;    // 256
    for (int i = tid; i < 48 * 256; i += 512) whinS[(i >> 8) * 264 + (i & 255)] = Whh_in[s * 12288 + i];
    for (int i = tid; i < 48 * 256; i += 512) whoS[(i >> 8) * 264 + (i & 255)] = Whh_out[s * 12288 + i];
    for (int i = tid; i < 32 * 256; i += 512) wqS[(i >> 8) * 264 + (i & 255)] = Wq[s * 8192 + i];
    __syncthreads();

#pragma unroll 1
    for (int t = 0; t < T_STEPS; t++) {
      const int par = t & 1;
      if (tid < 16) pollf(&gf[tid * 16], t + 1);
      __syncthreads();
      if (tid < 256) {
        float g0 = gld(ws + GIOV_OFF + tid);
        float g1 = gld(ws + GIOV_OFF + 256 + tid);
        float g2 = gld(ws + GIOV_OFF + 512 + tid);
        const float* gh = ws + GHOV_OFF + par * 768;
        float o0 = gld(gh + tid), o1 = gld(gh + 256 + tid), o2 = gld(gh + 512 + tid);
        float h1v = gld(ws + H1V_OFF + par * 256 + tid);
        float r = sigmoidf_(g0 + o0);
        float z = sigmoidf_(g1 + o1);
        float n = tanhf(g2 + r * o2);
        hS[tid] = (1.f - z) * n + z * h1v;
      }
      __syncthreads();
      // ghn slice
      {
        int r = tid >> 3, l = tid & 7;
        if (r < 48) {
          int m = s * 48 + r;
          float sm = 0.f;
#pragma unroll
          for (int jj = 0; jj < 8; jj++) {
            float4 w4 = *(const float4*)&whinS[r * 264 + jj * 32 + l * 4];
            float4 h4 = *(const float4*)&hS[jj * 32 + l * 4];
            sm += w4.x * h4.x + w4.y * h4.y + w4.z * h4.z + w4.w * h4.w;
          }
#pragma unroll
          for (int off = 4; off; off >>= 1) sm += __shfl_xor(sm, off, 8);
          if (l == 0) gst(ws + GHNV_OFF + m, sm + bhh_in[m]);
        }
      }
      __syncthreads();
      if (tid == 0) rel_store(&tf[s * 16], t + 1);
      if (tid == 0) pollf(&h1f[(s & 7) * 16], t + 1);
      __syncthreads();
      if (tid < 256) h1S[tid] = gld(ws + H1V_OFF + ((t + 1) & 1) * 256 + tid);
      __syncthreads();
      // gho(t+1) slice
      {
        int r = tid >> 3, l = tid & 7;
        if (r < 48) {
          int m = s * 48 + r;
          float sm = 0.f;
#pragma unroll
          for (int jj = 0; jj < 8; jj++) {
            float4 w4 = *(const float4*)&whoS[r * 264 + jj * 32 + l * 4];
            float4 h4 = *(const float4*)&h1S[jj * 32 + l * 4];
            sm += w4.x * h4.x + w4.y * h4.y + w4.z * h4.z + w4.w * h4.w;
          }
#pragma unroll
          for (int off = 4; off; off >>= 1) sm += __shfl_xor(sm, off, 8);
          if (l == 0) gst(ws + GHOV_OFF + ((t + 1) & 1) * 768 + m, sm + bhh_out[m]);
        }
      }
      // q(t+1) slice
      {
        int ap = tid >> 4, l = tid & 15;
        int a = s * 32 + ap;
        float sm = 0.f;
#pragma unroll
        for (int jj = 0; jj < 4; jj++) {
          float4 w4 = *(const float4*)&wqS[ap * 264 + jj * 64 + l * 4];
          float4 h4 = *(const float4*)&h1S[jj * 64 + l * 4];
          sm += w4.x * h4.x + w4.y * h4.y + w4.z * h4.z + w4.w * h4.w;
        }
#pragma unroll
        for (int off = 8; off; off >>= 1) sm += __shfl_xor(sm, off, 16);
        if (l == 0) gst(ws + QV_OFF + a, sm);
      }
      __syncthreads();
      if (tid < 8) rel_store(&tqr[(s * 8 + tid) * 16], t + 2);
    }

  } else if (bid < PSC0) {
    // ================= GIO g: gio rows from ctxv (direct CFR poll) =================
    const int g = bid - GIO0;
    float* wS  = S;           // [48][690]
    float* cvS = S + 33120;   // 704
    for (int i = tid; i < 48 * 684; i += 512) {
      int r = i / 684, c = i - r * 684;
      wS[r * 690 + c] = Wih_out[(g * 48 + r) * 684 + c];
    }
    __syncthreads();
#pragma unroll 1
    for (int t = 0; t < T_STEPS; t++) {
      if (tid < NCTXB) pollf(&cfr[(tid * 8 + (bid & 7)) * 16], t + 1);
      __syncthreads();
      for (int i = tid; i < 684; i += 512) cvS[i] = gld(ws + CTXV_OFF + i);
      __syncthreads();
      {
        int r = tid >> 3, l = tid & 7;
        if (r < 48) {
          float sm = 0.f;
          for (int k = l; k < 684; k += 8) sm += wS[r * 690 + k] * cvS[k];
#pragma unroll
          for (int off = 4; off; off >>= 1) sm += __shfl_xor(sm, off, 8);
          if (l == 0) {
            int m = g * 48 + r;
            gst(ws + GIOV_OFF + m, sm + bih_out[m]);
          }
        }
      }
      __syncthreads();
      if (tid == 0) rel_store(&gf[g * 16], t + 1);
    }

  } else {
    // ================= PSC p: psc rows from ctxv (direct CFR poll) =================
    const int p = bid - PSC0;
    float* wS  = S;           // [32][690]
    float* cvS = S + 22080;   // 704
    for (int i = tid; i < 32 * 684; i += 512) {
      int r = i / 684, c = i - r * 684;
      wS[r * 690 + c] = Wc_[(p * 32 + r) * 684 + c];
    }
    __syncthreads();
#pragma unroll 1
    for (int t = 0; t < T_STEPS; t++) {
      if (tid < NCTXB) pollf(&cfr[(tid * 8 + (bid & 7)) * 16], t + 1);
      __syncthreads();
      for (int i = tid; i < 684; i += 512) cvS[i] = gld(ws + CTXV_OFF + i);
      __syncthreads();
      {
        int r = tid >> 4, l = tid & 15;
        if (r < 32) {
          float sm = 0.f;
          for (int k = l; k < 684; k += 16) sm += wS[r * 690 + k] * cvS[k];
#pragma unroll
          for (int off = 8; off; off >>= 1) sm += __shfl_xor(sm, off, 16);
          if (l == 0) gst(ws + PSCV_OFF + p * 32 + r, sm);
        }
      }
      __syncthreads();
      if (tid == 0) rel_store(&pscf[p * 16], t + 1);
    }
  }
}

// ---------------- host ----------------

extern "C" void kernel_launch(void* const* d_in, const int* in_sizes, int n_in,
                              void* d_out, int out_size, void* d_ws, size_t ws_size,
                              hipStream_t stream) {
  (void)in_sizes; (void)n_in; (void)out_size; (void)ws_size;
  const float* cnn      = (const float*)d_in[0];
  const float* imask    = (const float*)d_in[1];
  const float* emb_tab  = (const float*)d_in[2];
  const float* W_init   = (const float*)d_in[3];
  const float* b_init   = (const float*)d_in[4];
  const float* Wih_in   = (const float*)d_in[5];
  const float* Whh_in   = (const float*)d_in[6];
  const float* bih_in   = (const float*)d_in[7];
  const float* bhh_in   = (const float*)d_in[8];
  const float* Wih_out  = (const float*)d_in[9];
  const float* Whh_out  = (const float*)d_in[10];
  const float* bih_out  = (const float*)d_in[11];
  const float* bhh_out  = (const float*)d_in[12];
  const float* Wq       = (const float*)d_in[13];
  const float* bq       = (const float*)d_in[14];
  const float* Wproj    = (const float*)d_in[15];
  const float* bproj    = (const float*)d_in[16];
  const float* convk    = (const float*)d_in[17];
  const float* Wcov     = (const float*)d_in[18];
  const float* wa       = (const float*)d_in[19];
  const float* ba       = (const float*)d_in[20];
  const float* Ws_      = (const float*)d_in[21];
  const float* bs_      = (const float*)d_in[22];
  const float* We_      = (const float*)d_in[23];
  const float* be_      = (const float*)d_in[24];
  const float* Wc_      = (const float*)d_in[25];
  const float* bc_      = (const float*)d_in[26];
  const float* Wv_      = (const float*)d_in[27];
  const float* bv_      = (const float*)d_in[28];
  float* ws  = (float*)d_ws;
  float* out = (float*)d_out;

  k_init<<<1, 256, 0, stream>>>(imask, ws);
  k_avg<<<C_DIM, 256, 0, stream>>>(cnn, ws);
  k_h0<<<1, 256, 0, stream>>>(W_init, b_init, ws);
  k_km<<<121, 512, 0, stream>>>(convk, Wcov, ws);
  k_ct<<<dim3(HW / 128, A_DIM / 64), 256, 0, stream>>>(cnn, Wproj, bproj, ws);
  k_gi<<<V_DIM, 256, 0, stream>>>(emb_tab, Wih_in, bih_in, ws);
  k_se<<<V_DIM, 128, 0, stream>>>(emb_tab, We_, be_, ws);
  k_tr<<<512, 256, 0, stream>>>(Ws_, ws + WST_OFF, 128, 256);
  k_tr<<<512, 256, 0, stream>>>(Wv_, ws + WVT_OFF, 415, 128);
  k_pre0<<<16, 512, 0, stream>>>(Whh_in, bhh_in, ws);
  k_pre1<<<16, 512, 0, stream>>>(Wq, Whh_out, bhh_out, ws);
  k_go<<<1, 256, 0, stream>>>(ws);

  k_steps<<<NGRID, 512, 0, stream>>>(cnn, Whh_in, Whh_out, Wq, Wih_out, Wc_,
                                     bq, wa, ba, bih_out, bhh_out, bhh_in,
                                     bs_, bc_, bv_, ws, out);
}